// Round 1
// baseline (895.356 us; speedup 1.0000x reference)
//
#include <hip/hip_runtime.h>

// ---------------------------------------------------------------------------
// ZambaSharedBlock: GQA attention block w/ qk-l2norm + FFN + 3 LayerNorms
// B=2 S=2048 DIM=2048 H=16 G=4 DH=128 FF=8192, non-causal, QK_SCALE=10
// Round 1: correctness-first bf16 MFMA pipeline (m97-style 128x128 GEMM,
// flash attention 64-row Q blocks). All intermediates bf16 in d_ws.
// ---------------------------------------------------------------------------

typedef __attribute__((ext_vector_type(8))) short short8;
typedef __attribute__((ext_vector_type(4))) float f32x4;

__device__ __forceinline__ unsigned short f2bf(float f) {
  unsigned int u = __builtin_bit_cast(unsigned int, f);
  u += 0x7FFFu + ((u >> 16) & 1u);           // RNE
  return (unsigned short)(u >> 16);
}
__device__ __forceinline__ float bf2f(unsigned short h) {
  unsigned int u = ((unsigned int)h) << 16;
  return __builtin_bit_cast(float, u);
}

typedef const void __attribute__((address_space(1)))* gas1_t;
typedef void __attribute__((address_space(3)))* las3_t;
#define GLDS16(g, l) \
  __builtin_amdgcn_global_load_lds((gas1_t)(const void*)(g), (las3_t)(void*)(l), 16, 0, 0)

// ---------------------------------------------------------------------------
// cast f32 -> bf16, 4 elems/thread (n must be divisible by 1024)
__global__ __launch_bounds__(256) void cast_f32_bf16(const float* __restrict__ src,
                                                     unsigned short* __restrict__ dst,
                                                     int n) {
  int i = (blockIdx.x * 256 + threadIdx.x) * 4;
  if (i >= n) return;
  float4 f = *(const float4*)(src + i);
  uint2 u;
  u.x = (unsigned)f2bf(f.x) | ((unsigned)f2bf(f.y) << 16);
  u.y = (unsigned)f2bf(f.z) | ((unsigned)f2bf(f.w) << 16);
  *(uint2*)(dst + i) = u;
}

// ---------------------------------------------------------------------------
// transpose+cast: src f32 [R][C] -> dst bf16 [C][R] (dst row offset for packing
// wq|wk|wv into one [3072][2048] B^T matrix). block (32,8), grid (C/32, R/32).
__global__ void transcast(const float* __restrict__ src, unsigned short* __restrict__ dst,
                          int R, int C, int dst_ld, int row_off) {
  __shared__ float t[32][33];
  const int tx = threadIdx.x, ty = threadIdx.y;
  const int c0 = blockIdx.x * 32, r0 = blockIdx.y * 32;
#pragma unroll
  for (int j = 0; j < 4; ++j)
    t[ty + j * 8][tx] = src[(size_t)(r0 + ty + j * 8) * C + c0 + tx];
  __syncthreads();
#pragma unroll
  for (int j = 0; j < 4; ++j)
    dst[(size_t)(row_off + c0 + ty + j * 8) * dst_ld + r0 + tx] = f2bf(t[tx][ty + j * 8]);
}

// ---------------------------------------------------------------------------
// m97-style GEMM: C[M][N] = A[M][K] * Bt[N][K]^T, all bf16, f32 accum.
// 128x128 tile, BK=64, 4 waves (each 64x64), 16x16x32 MFMA.
__global__ __launch_bounds__(256) void gemm128(const unsigned short* __restrict__ A,
                                               const unsigned short* __restrict__ Bt,
                                               unsigned short* __restrict__ C,
                                               int M, int N, int K) {
  __shared__ unsigned short As[128 * 64];  // [row][k] linear (global_load_lds dest)
  __shared__ unsigned short Bs[128 * 64];  // [col][k] linear
  const int tid = threadIdx.x;
  const int w = tid >> 6, l = tid & 63;
  const int wr = w >> 1, wc = w & 1;
  const int brow = blockIdx.y * 128, bcol = blockIdx.x * 128;

  const unsigned short* aSrc = A + (size_t)(brow + w * 8 + (l >> 3)) * K + (l & 7) * 8;
  const unsigned short* bSrc = Bt + (size_t)(bcol + w * 8 + (l >> 3)) * K + (l & 7) * 8;
  unsigned short* aDst = &As[w * 512 + l * 8];
  unsigned short* bDst = &Bs[w * 512 + l * 8];
  const size_t rstride = (size_t)32 * K;

  f32x4 acc[4][4];
#pragma unroll
  for (int m = 0; m < 4; ++m)
#pragma unroll
    for (int n = 0; n < 4; ++n) acc[m][n] = (f32x4){0.f, 0.f, 0.f, 0.f};

  for (int kt = 0; kt < K; kt += 64) {
    __syncthreads();  // previous tile fully consumed
#pragma unroll
    for (int i = 0; i < 4; ++i) {
      GLDS16(aSrc + i * rstride + kt, aDst + i * 2048);
      GLDS16(bSrc + i * rstride + kt, bDst + i * 2048);
    }
    __syncthreads();  // compiler drains vmcnt before s_barrier
#pragma unroll
    for (int kk = 0; kk < 2; ++kk) {
      short8 af[4], bfr[4];
#pragma unroll
      for (int m = 0; m < 4; ++m)
        af[m] = *(const short8*)&As[(wr * 64 + m * 16 + (l & 15)) * 64 + kk * 32 + (l >> 4) * 8];
#pragma unroll
      for (int n = 0; n < 4; ++n)
        bfr[n] = *(const short8*)&Bs[(wc * 64 + n * 16 + (l & 15)) * 64 + kk * 32 + (l >> 4) * 8];
#pragma unroll
      for (int m = 0; m < 4; ++m)
#pragma unroll
        for (int n = 0; n < 4; ++n)
          acc[m][n] = __builtin_amdgcn_mfma_f32_16x16x32_bf16(af[m], bfr[n], acc[m][n], 0, 0, 0);
    }
  }
  // C/D layout: col = lane&15, row = (lane>>4)*4 + reg  [m89-verified]
#pragma unroll
  for (int m = 0; m < 4; ++m)
#pragma unroll
    for (int r = 0; r < 4; ++r) {
      const int row = brow + wr * 64 + m * 16 + (l >> 4) * 4 + r;
#pragma unroll
      for (int n = 0; n < 4; ++n) {
        const int col = bcol + wc * 64 + n * 16 + (l & 15);
        C[(size_t)row * N + col] = f2bf(acc[m][n][r]);
      }
    }
}

// ---------------------------------------------------------------------------
// l2-normalize q (cols 0..2047, x10 scale) and k (cols 2048..2559) per
// (token, head) over 128 dims. One wave per unit; 2 elems/lane. In-place.
__global__ __launch_bounds__(256) void l2norm_qk(unsigned short* __restrict__ qkv) {
  const int wid = blockIdx.x * 4 + (threadIdx.x >> 6);
  const int l = threadIdx.x & 63;
  const int token = wid / 20, u = wid % 20;
  const int col = (u < 16) ? u * 128 : 2048 + (u - 16) * 128;
  unsigned short* p = qkv + (size_t)token * 3072 + col + l * 2;
  const float a = bf2f(p[0]), b = bf2f(p[1]);
  float ss = a * a + b * b;
#pragma unroll
  for (int m = 1; m < 64; m <<= 1) ss += __shfl_xor(ss, m);
  const float sc = ((u < 16) ? 10.f : 1.f) / fmaxf(sqrtf(ss), 1e-12f);
  p[0] = f2bf(a * sc);
  p[1] = f2bf(b * sc);
}

// ---------------------------------------------------------------------------
// V transpose: qkv v-part [token][2560 + g*128 + d] -> vt[(b*4+g)*128 + d][s]
__global__ __launch_bounds__(256) void vtrans(const unsigned short* __restrict__ qkv,
                                              unsigned short* __restrict__ vt) {
  const int idx = blockIdx.x * 256 + threadIdx.x;  // 2*4*128*2048 total
  const int s_ = idx & 2047;
  const int rest = idx >> 11;
  const int d = rest & 127;
  const int bg = rest >> 7;
  const int b = bg >> 2, g = bg & 3;
  vt[idx] = qkv[(size_t)(b * 2048 + s_) * 3072 + 2560 + g * 128 + d];
}

// ---------------------------------------------------------------------------
// Flash attention: grid (S/64, B*H). 4 waves x 16 q-rows. KV tiles of 64.
// q pre-scaled by 10 and l2-normed; k l2-normed. Non-causal full softmax.
__global__ __launch_bounds__(256) void attn_kernel(const unsigned short* __restrict__ qkv,
                                                   const unsigned short* __restrict__ vt,
                                                   unsigned short* __restrict__ out) {
  __shared__ unsigned short Kl[64 * 136];   // [key][d], pad 136 (2-way banks)
  __shared__ unsigned short Vl[128 * 72];   // [d][key], pad 72
  __shared__ unsigned short Pl[4 * 16 * 72];// per-wave P [16][72]
  const int tid = threadIdx.x, w = tid >> 6, l = tid & 63;
  const int bh = blockIdx.y, b = bh >> 4, h = bh & 15, g = h >> 2;
  const int q0 = blockIdx.x * 64;

  // Q fragments in registers: rows = l&15 (wave-local), k along 128 dims
  short8 qf[4];
  {
    const unsigned short* qrow =
        qkv + (size_t)(b * 2048 + q0 + w * 16 + (l & 15)) * 3072 + h * 128;
#pragma unroll
    for (int kk = 0; kk < 4; ++kk)
      qf[kk] = *(const short8*)&qrow[kk * 32 + (l >> 4) * 8];
  }

  f32x4 o[8];
#pragma unroll
  for (int n = 0; n < 8; ++n) o[n] = (f32x4){0.f, 0.f, 0.f, 0.f};
  float m_r[4] = {-1e30f, -1e30f, -1e30f, -1e30f};
  float l_r[4] = {0.f, 0.f, 0.f, 0.f};

  const unsigned short* kbase = qkv + (size_t)(b * 2048) * 3072 + 2048 + g * 128;
  const unsigned short* vbase = vt + (size_t)(b * 4 + g) * 128 * 2048;

  for (int t = 0; t < 32; ++t) {
    const int kv0 = t * 64;
    __syncthreads();  // previous tile's PV reads done
#pragma unroll
    for (int i = 0; i < 4; ++i) {  // K tile: 64 keys x 128 d
      const int row = i * 16 + (tid >> 4), ce = (tid & 15) * 8;
      *(uint4*)&Kl[row * 136 + ce] = *(const uint4*)&kbase[(size_t)(kv0 + row) * 3072 + ce];
    }
#pragma unroll
    for (int i = 0; i < 4; ++i) {  // Vt tile: 128 d x 64 keys
      const int d = i * 32 + (tid >> 3), ce = (tid & 7) * 8;
      *(uint4*)&Vl[d * 72 + ce] = *(const uint4*)&vbase[(size_t)d * 2048 + kv0 + ce];
    }
    __syncthreads();

    // QK^T: S[16 rows][64 keys] per wave
    f32x4 s[4];
#pragma unroll
    for (int c = 0; c < 4; ++c) s[c] = (f32x4){0.f, 0.f, 0.f, 0.f};
#pragma unroll
    for (int kk = 0; kk < 4; ++kk)
#pragma unroll
      for (int c = 0; c < 4; ++c) {
        short8 kf = *(const short8*)&Kl[(c * 16 + (l & 15)) * 136 + kk * 32 + (l >> 4) * 8];
        s[c] = __builtin_amdgcn_mfma_f32_16x16x32_bf16(qf[kk], kf, s[c], 0, 0, 0);
      }

    // online softmax; D-layout rows = (l>>4)*4+r, cols = c*16+(l&15)
    float alpha[4];
#pragma unroll
    for (int r = 0; r < 4; ++r) {
      float tm = fmaxf(fmaxf(s[0][r], s[1][r]), fmaxf(s[2][r], s[3][r]));
#pragma unroll
      for (int mm = 1; mm < 16; mm <<= 1) tm = fmaxf(tm, __shfl_xor(tm, mm));
      const float mn = fmaxf(m_r[r], tm);
      float ps = 0.f;
#pragma unroll
      for (int c = 0; c < 4; ++c) {
        const float p = __expf(s[c][r] - mn);
        s[c][r] = p;
        ps += p;
      }
#pragma unroll
      for (int mm = 1; mm < 16; mm <<= 1) ps += __shfl_xor(ps, mm);
      alpha[r] = __expf(m_r[r] - mn);
      l_r[r] = l_r[r] * alpha[r] + ps;
      m_r[r] = mn;
    }
#pragma unroll
    for (int n = 0; n < 8; ++n)
#pragma unroll
      for (int r = 0; r < 4; ++r) o[n][r] *= alpha[r];

    // stage P (bf16) to per-wave LDS in A-operand layout [qrow][key]
#pragma unroll
    for (int c = 0; c < 4; ++c)
#pragma unroll
      for (int r = 0; r < 4; ++r)
        Pl[w * 1152 + ((l >> 4) * 4 + r) * 72 + c * 16 + (l & 15)] = f2bf(s[c][r]);
    __syncthreads();

    // PV: O[16][128] += P[16][64] * V[64][128]
#pragma unroll
    for (int kk = 0; kk < 2; ++kk) {
      short8 pf = *(const short8*)&Pl[w * 1152 + (l & 15) * 72 + kk * 32 + (l >> 4) * 8];
#pragma unroll
      for (int n = 0; n < 8; ++n) {
        short8 vf = *(const short8*)&Vl[(n * 16 + (l & 15)) * 72 + kk * 32 + (l >> 4) * 8];
        o[n] = __builtin_amdgcn_mfma_f32_16x16x32_bf16(pf, vf, o[n], 0, 0, 0);
      }
    }
  }

  unsigned short* orow = out + (size_t)(b * 2048 + q0 + w * 16) * 2048 + h * 128;
#pragma unroll
  for (int r = 0; r < 4; ++r) {
    const float inv = 1.f / l_r[r];
    const int row = (l >> 4) * 4 + r;
#pragma unroll
    for (int n = 0; n < 8; ++n)
      orow[(size_t)row * 2048 + n * 16 + (l & 15)] = f2bf(o[n][r] * inv);
  }
}

// ---------------------------------------------------------------------------
// Row LayerNorm (block per row): optional bias-add, optional SiLU, then LN.
// src bf16; dst bf16 (may alias src) or f32.
template <int NC, bool BIAS, bool SILU, bool OUTF32>
__global__ __launch_bounds__(256) void ln_row(const unsigned short* __restrict__ src,
                                              unsigned short* __restrict__ dstb,
                                              float* __restrict__ dstf,
                                              const float* __restrict__ gamma,
                                              const float* __restrict__ beta,
                                              const float* __restrict__ bias) {
  constexpr int E = NC / 256;
  const int row = blockIdx.x, tid = threadIdx.x;
  const size_t base = (size_t)row * NC + tid * E;
  float v[E];
#pragma unroll
  for (int c = 0; c < E / 8; ++c) {
    uint4 u = *(const uint4*)(src + base + c * 8);
    const unsigned short* us = (const unsigned short*)&u;
#pragma unroll
    for (int j = 0; j < 8; ++j) v[c * 8 + j] = bf2f(us[j]);
  }
  if constexpr (BIAS) {
#pragma unroll
    for (int i = 0; i < E; ++i) v[i] += bias[tid * E + i];
  }
  if constexpr (SILU) {
#pragma unroll
    for (int i = 0; i < E; ++i) v[i] = v[i] / (1.f + __expf(-v[i]));
  }
  float s = 0.f, q = 0.f;
#pragma unroll
  for (int i = 0; i < E; ++i) {
    s += v[i];
    q += v[i] * v[i];
  }
#pragma unroll
  for (int m = 1; m < 64; m <<= 1) {
    s += __shfl_xor(s, m);
    q += __shfl_xor(q, m);
  }
  __shared__ float rs[4], rq[4];
  if ((tid & 63) == 0) {
    rs[tid >> 6] = s;
    rq[tid >> 6] = q;
  }
  __syncthreads();
  s = rs[0] + rs[1] + rs[2] + rs[3];
  q = rq[0] + rq[1] + rq[2] + rq[3];
  const float mean = s / NC;
  const float rstd = rsqrtf(q / NC - mean * mean + 1e-5f);
#pragma unroll
  for (int i = 0; i < E; ++i)
    v[i] = (v[i] - mean) * rstd * gamma[tid * E + i] + beta[tid * E + i];
  if constexpr (OUTF32) {
#pragma unroll
    for (int c = 0; c < E / 4; ++c) {
      float4 f = {v[c * 4], v[c * 4 + 1], v[c * 4 + 2], v[c * 4 + 3]};
      *(float4*)(dstf + base + c * 4) = f;
    }
  } else {
#pragma unroll
    for (int c = 0; c < E / 8; ++c) {
      uint4 u;
      unsigned* up = (unsigned*)&u;
#pragma unroll
      for (int j = 0; j < 4; ++j)
        up[j] = (unsigned)f2bf(v[c * 8 + j * 2]) | ((unsigned)f2bf(v[c * 8 + j * 2 + 1]) << 16);
      *(uint4*)(dstb + base + c * 8) = u;
    }
  }
}

// ---------------------------------------------------------------------------
extern "C" void kernel_launch(void* const* d_in, const int* in_sizes, int n_in,
                              void* d_out, int out_size, void* d_ws, size_t ws_size,
                              hipStream_t stream) {
  (void)in_sizes; (void)n_in; (void)out_size; (void)ws_size;
  const float* x     = (const float*)d_in[0];
  const float* wq    = (const float*)d_in[1];
  const float* wk    = (const float*)d_in[2];
  const float* wv    = (const float*)d_in[3];
  const float* wo    = (const float*)d_in[4];
  const float* ln1_g = (const float*)d_in[5];
  const float* ln1_b = (const float*)d_in[6];
  const float* w1    = (const float*)d_in[7];
  const float* b1    = (const float*)d_in[8];
  const float* lnf_g = (const float*)d_in[9];
  const float* lnf_b = (const float*)d_in[10];
  const float* w2    = (const float*)d_in[11];
  const float* b2    = (const float*)d_in[12];

  unsigned short* ws = (unsigned short*)d_ws;
  unsigned short* wqkvT  = ws;                                  // [3072][2048]
  unsigned short* woT    = wqkvT  + (size_t)3072 * 2048;        // [2048][2048]
  unsigned short* w1T    = woT    + (size_t)2048 * 2048;        // [8192][2048]
  unsigned short* w2T    = w1T    + (size_t)8192 * 2048;        // [2048][8192]
  unsigned short* xb     = w2T    + (size_t)2048 * 8192;        // x bf16; later o/h
  unsigned short* qkv    = xb     + (size_t)4096 * 2048;        // [4096][3072]; later y
  unsigned short* vt     = qkv    + (size_t)4096 * 3072;        // [8][128][2048]
  unsigned short* attn_o = vt     + (size_t)4096 * 512;         // [4096][2048]
  unsigned short* f1     = attn_o + (size_t)4096 * 2048;        // [4096][8192] in-place f

  const dim3 tb(32, 8);
  // prep: casts + weight transposes
  cast_f32_bf16<<<8192, 256, 0, stream>>>(x, xb, 4096 * 2048);
  transcast<<<dim3(64, 64),  tb, 0, stream>>>(wq, wqkvT, 2048, 2048, 2048, 0);
  transcast<<<dim3(16, 64),  tb, 0, stream>>>(wk, wqkvT, 2048, 512, 2048, 2048);
  transcast<<<dim3(16, 64),  tb, 0, stream>>>(wv, wqkvT, 2048, 512, 2048, 2560);
  transcast<<<dim3(64, 64),  tb, 0, stream>>>(wo, woT, 2048, 2048, 2048, 0);
  transcast<<<dim3(256, 64), tb, 0, stream>>>(w1, w1T, 2048, 8192, 2048, 0);
  transcast<<<dim3(64, 256), tb, 0, stream>>>(w2, w2T, 8192, 2048, 8192, 0);

  // fused QKV projection
  gemm128<<<dim3(24, 32), 256, 0, stream>>>(xb, wqkvT, qkv, 4096, 3072, 2048);
  // qk-norm (+fold QK_SCALE into q), V transpose for attention
  l2norm_qk<<<20480, 256, 0, stream>>>(qkv);
  vtrans<<<8192, 256, 0, stream>>>(qkv, vt);
  // flash attention
  attn_kernel<<<dim3(32, 32), 256, 0, stream>>>(qkv, vt, attn_o);
  // O projection (into xb region) + post-attn LN (in-place)
  gemm128<<<dim3(16, 32), 256, 0, stream>>>(attn_o, woT, xb, 4096, 2048, 2048);
  ln_row<2048, false, false, false><<<4096, 256, 0, stream>>>(xb, xb, nullptr, ln1_g, ln1_b, nullptr);
  // FFN1 + bias + SiLU + LN (in-place on f1)
  gemm128<<<dim3(64, 32), 256, 0, stream>>>(xb, w1T, f1, 4096, 8192, 2048);
  ln_row<8192, true, true, false><<<4096, 256, 0, stream>>>(f1, f1, nullptr, lnf_g, lnf_b, b1);
  // FFN2 (into qkv region) + bias + final LN -> f32 d_out
  gemm128<<<dim3(16, 32), 256, 0, stream>>>(f1, w2T, qkv, 4096, 2048, 8192);
  ln_row<2048, true, false, true><<<4096, 256, 0, stream>>>(qkv, nullptr, (float*)d_out, ln1_g, ln1_b, b2);
}

// Round 2
// 748.752 us; speedup vs baseline: 1.1958x; 1.1958x over previous
//
#include <hip/hip_runtime.h>

// ---------------------------------------------------------------------------
// ZambaSharedBlock: GQA attention block w/ qk-l2norm + FFN + 3 LayerNorms
// B=2 S=2048 DIM=2048 H=16 G=4 DH=128 FF=8192, non-causal, QK_SCALE=10
// Round 2: 8-phase-style pipelined GEMM (256xBN tile, K-split halves, counted
// vmcnt, XOR LDS swizzle, setprio). Attention/LN unchanged from round 1.
// ---------------------------------------------------------------------------

typedef __attribute__((ext_vector_type(8))) short short8;
typedef __attribute__((ext_vector_type(4))) float f32x4;

__device__ __forceinline__ unsigned short f2bf(float f) {
  unsigned int u = __builtin_bit_cast(unsigned int, f);
  u += 0x7FFFu + ((u >> 16) & 1u);           // RNE
  return (unsigned short)(u >> 16);
}
__device__ __forceinline__ float bf2f(unsigned short h) {
  unsigned int u = ((unsigned int)h) << 16;
  return __builtin_bit_cast(float, u);
}

typedef const void __attribute__((address_space(1)))* gas1_t;
typedef void __attribute__((address_space(3)))* las3_t;
#define GLDS16(g, l) \
  __builtin_amdgcn_global_load_lds((gas1_t)(const void*)(g), (las3_t)(void*)(l), 16, 0, 0)

// ---------------------------------------------------------------------------
// cast f32 -> bf16, 4 elems/thread
__global__ __launch_bounds__(256) void cast_f32_bf16(const float* __restrict__ src,
                                                     unsigned short* __restrict__ dst,
                                                     int n) {
  int i = (blockIdx.x * 256 + threadIdx.x) * 4;
  if (i >= n) return;
  float4 f = *(const float4*)(src + i);
  uint2 u;
  u.x = (unsigned)f2bf(f.x) | ((unsigned)f2bf(f.y) << 16);
  u.y = (unsigned)f2bf(f.z) | ((unsigned)f2bf(f.w) << 16);
  *(uint2*)(dst + i) = u;
}

// ---------------------------------------------------------------------------
// transpose+cast: src f32 [R][C] -> dst bf16 [C][R] (+row_off for qkv packing)
__global__ void transcast(const float* __restrict__ src, unsigned short* __restrict__ dst,
                          int R, int C, int dst_ld, int row_off) {
  __shared__ float t[32][33];
  const int tx = threadIdx.x, ty = threadIdx.y;
  const int c0 = blockIdx.x * 32, r0 = blockIdx.y * 32;
#pragma unroll
  for (int j = 0; j < 4; ++j)
    t[ty + j * 8][tx] = src[(size_t)(r0 + ty + j * 8) * C + c0 + tx];
  __syncthreads();
#pragma unroll
  for (int j = 0; j < 4; ++j)
    dst[(size_t)(row_off + c0 + ty + j * 8) * dst_ld + r0 + tx] = f2bf(t[tx][ty + j * 8]);
}

// ---------------------------------------------------------------------------
// Pipelined GEMM: C[M][N] = A[M][K] * Bt[N][K]^T, bf16 in, f32 acc, bf16 out.
// Tile 256 x BN, BK=64, 8 waves (2Mx4N). K-split halves H0=A_k0 H1=B_k0
// H2=A_k1 H3=B_k1, double-buffered. Per tile: 4 phases, each = {ds_read frags,
// issue one half-tile prefetch of tile t+1, setprio(1), MFMA cluster}.
// Counted vmcnt at p0/p2 only (never 0). LDS swizzle g=((row<<2)|slot)^(row&7)
// (16B units) applied on the READ; global_load_lds dest stays LINEAR and the
// SOURCE address applies the inverse permutation (rule #21).
template <int BN>
__global__ __launch_bounds__(512, 2) void gemm256(const unsigned short* __restrict__ A,
                                                  const unsigned short* __restrict__ Bt,
                                                  unsigned short* __restrict__ C,
                                                  int M, int N, int K) {
  constexpr int NF = BN / 64;            // n-frags per wave (4 or 2)
  constexpr int HB = BN * 64;            // B-half bytes (16K or 8K)
  constexpr int RB = BN / 128;           // B stage rounds per half (2 or 1)
  constexpr int AK1 = 16384 + HB;        // per-kstep region stride; A_k1 offset
  constexpr int BUFB = 32768 + 2 * HB;   // bytes per dbuf buffer
  extern __shared__ char lds[];

  const int tid = threadIdx.x, l = tid & 63, w = tid >> 6;
  const int wr = w >> 2, wc = w & 3;
  const int brow = blockIdx.y * 256, bcol = blockIdx.x * BN;
  const unsigned short* Aa = A + (size_t)brow * K;
  const unsigned short* Bb = Bt + (size_t)bcol * K;
  const int NT = K >> 6;

  // per-thread swizzled read offsets (bytes within a half region)
  const int slot = l >> 4;
  const int rowA = wr * 128 + (l & 15);
  const int aRd = ((((rowA << 2) | slot) << 4) ^ ((rowA & 7) << 4));
  const int rowB = wc * (BN / 4) + (l & 15);
  const int bRd = ((((rowB << 2) | slot) << 4) ^ ((rowB & 7) << 4));

  f32x4 acc[8][NF];
#pragma unroll
  for (int m = 0; m < 8; ++m)
#pragma unroll
    for (int n = 0; n < NF; ++n) acc[m][n] = (f32x4){0.f, 0.f, 0.f, 0.f};

  // stage one A half (256 rows x 32 k) / B half (BN rows x 32 k): linear LDS
  // dest slot g=r*512+tid; source = inverse-swizzled (row,slot) of g.
  auto stageA = [&](char* dst, int kofs) {
#pragma unroll
    for (int r = 0; r < 2; ++r) {
      const int g = r * 512 + tid;
      const int rw = ((g >> 3) << 1) | (((g >> 2) ^ (g >> 4)) & 1);
      const int sl = (g ^ rw) & 3;
      GLDS16(Aa + (size_t)rw * K + kofs + sl * 8, dst + g * 16);
    }
  };
  auto stageB = [&](char* dst, int kofs) {
#pragma unroll
    for (int r = 0; r < RB; ++r) {
      const int g = r * 512 + tid;
      const int rw = ((g >> 3) << 1) | (((g >> 2) ^ (g >> 4)) & 1);
      const int sl = (g ^ rw) & 3;
      GLDS16(Bb + (size_t)rw * K + kofs + sl * 8, dst + g * 16);
    }
  };

  // prologue: stage all 4 halves of tile 0 into buf0
  stageA(lds, 0);
  stageB(lds + 16384, 0);
  stageA(lds + AK1, 32);
  stageB(lds + AK1 + 16384, 32);

  int kt = 0;
  for (int t = 0; t < NT; ++t) {
    char* curb = lds + (t & 1) * BUFB;
    char* nxtb = lds + ((t & 1) ^ 1) * BUFB;
    const int ktn = (t + 1 < NT) ? kt + 64 : 0;  // last tile re-stages tile 0
    short8 af[4], bf[NF];

    // ---- phase 0: ks0, m-frags 0-3. Wait retires H0,H1 (leaves H2,H3).
    if constexpr (BN == 256) asm volatile("s_waitcnt vmcnt(4)" ::: "memory");
    else                     asm volatile("s_waitcnt vmcnt(3)" ::: "memory");
    asm volatile("s_barrier" ::: "memory");
#pragma unroll
    for (int n = 0; n < NF; ++n) bf[n] = *(const short8*)(curb + 16384 + bRd + n * 1024);
#pragma unroll
    for (int m = 0; m < 4; ++m) af[m] = *(const short8*)(curb + aRd + m * 1024);
    stageA(nxtb, ktn);
    __builtin_amdgcn_s_setprio(1);
#pragma unroll
    for (int m = 0; m < 4; ++m)
#pragma unroll
      for (int n = 0; n < NF; ++n)
        acc[m][n] = __builtin_amdgcn_mfma_f32_16x16x32_bf16(af[m], bf[n], acc[m][n], 0, 0, 0);
    __builtin_amdgcn_s_setprio(0);

    // ---- phase 1: ks0, m-frags 4-7 (same halves; barrier is pacing only)
    asm volatile("s_barrier" ::: "memory");
#pragma unroll
    for (int m = 0; m < 4; ++m) af[m] = *(const short8*)(curb + aRd + (m + 4) * 1024);
    stageB(nxtb + 16384, ktn);
    __builtin_amdgcn_s_setprio(1);
#pragma unroll
    for (int m = 0; m < 4; ++m)
#pragma unroll
      for (int n = 0; n < NF; ++n)
        acc[m + 4][n] = __builtin_amdgcn_mfma_f32_16x16x32_bf16(af[m], bf[n], acc[m + 4][n], 0, 0, 0);
    __builtin_amdgcn_s_setprio(0);

    // ---- phase 2: ks1, m-frags 0-3. Wait retires H2,H3 (leaves H0',H1').
    if constexpr (BN == 256) asm volatile("s_waitcnt vmcnt(4)" ::: "memory");
    else                     asm volatile("s_waitcnt vmcnt(3)" ::: "memory");
    asm volatile("s_barrier" ::: "memory");
#pragma unroll
    for (int n = 0; n < NF; ++n) bf[n] = *(const short8*)(curb + AK1 + 16384 + bRd + n * 1024);
#pragma unroll
    for (int m = 0; m < 4; ++m) af[m] = *(const short8*)(curb + AK1 + aRd + m * 1024);
    stageA(nxtb + AK1, ktn + 32);
    __builtin_amdgcn_s_setprio(1);
#pragma unroll
    for (int m = 0; m < 4; ++m)
#pragma unroll
      for (int n = 0; n < NF; ++n)
        acc[m][n] = __builtin_amdgcn_mfma_f32_16x16x32_bf16(af[m], bf[n], acc[m][n], 0, 0, 0);
    __builtin_amdgcn_s_setprio(0);

    // ---- phase 3: ks1, m-frags 4-7
    asm volatile("s_barrier" ::: "memory");
#pragma unroll
    for (int m = 0; m < 4; ++m) af[m] = *(const short8*)(curb + AK1 + aRd + (m + 4) * 1024);
    stageB(nxtb + AK1 + 16384, ktn + 32);
    __builtin_amdgcn_s_setprio(1);
#pragma unroll
    for (int m = 0; m < 4; ++m)
#pragma unroll
      for (int n = 0; n < NF; ++n)
        acc[m + 4][n] = __builtin_amdgcn_mfma_f32_16x16x32_bf16(af[m], bf[n], acc[m + 4][n], 0, 0, 0);
    __builtin_amdgcn_s_setprio(0);

    kt += 64;
  }

  // epilogue: C/D layout col=lane&15, row=(lane>>4)*4+reg
#pragma unroll
  for (int m = 0; m < 8; ++m)
#pragma unroll
    for (int r = 0; r < 4; ++r) {
      const int row = brow + wr * 128 + m * 16 + (l >> 4) * 4 + r;
#pragma unroll
      for (int n = 0; n < NF; ++n) {
        const int col = bcol + wc * (BN / 4) + n * 16 + (l & 15);
        C[(size_t)row * N + col] = f2bf(acc[m][n][r]);
      }
    }
}

// ---------------------------------------------------------------------------
// l2-normalize q (x10) and k per (token, head) over 128 dims. In-place.
__global__ __launch_bounds__(256) void l2norm_qk(unsigned short* __restrict__ qkv) {
  const int wid = blockIdx.x * 4 + (threadIdx.x >> 6);
  const int l = threadIdx.x & 63;
  const int token = wid / 20, u = wid % 20;
  const int col = (u < 16) ? u * 128 : 2048 + (u - 16) * 128;
  unsigned short* p = qkv + (size_t)token * 3072 + col + l * 2;
  const float a = bf2f(p[0]), b = bf2f(p[1]);
  float ss = a * a + b * b;
#pragma unroll
  for (int m = 1; m < 64; m <<= 1) ss += __shfl_xor(ss, m);
  const float sc = ((u < 16) ? 10.f : 1.f) / fmaxf(sqrtf(ss), 1e-12f);
  p[0] = f2bf(a * sc);
  p[1] = f2bf(b * sc);
}

// ---------------------------------------------------------------------------
// V transpose: qkv v-part -> vt[(b*4+g)*128 + d][s]
__global__ __launch_bounds__(256) void vtrans(const unsigned short* __restrict__ qkv,
                                              unsigned short* __restrict__ vt) {
  const int idx = blockIdx.x * 256 + threadIdx.x;
  const int s_ = idx & 2047;
  const int rest = idx >> 11;
  const int d = rest & 127;
  const int bg = rest >> 7;
  const int b = bg >> 2, g = bg & 3;
  vt[idx] = qkv[(size_t)(b * 2048 + s_) * 3072 + 2560 + g * 128 + d];
}

// ---------------------------------------------------------------------------
// Flash attention: grid (S/64, B*H). 4 waves x 16 q-rows. KV tiles of 64.
__global__ __launch_bounds__(256) void attn_kernel(const unsigned short* __restrict__ qkv,
                                                   const unsigned short* __restrict__ vt,
                                                   unsigned short* __restrict__ out) {
  __shared__ unsigned short Kl[64 * 136];
  __shared__ unsigned short Vl[128 * 72];
  __shared__ unsigned short Pl[4 * 16 * 72];
  const int tid = threadIdx.x, w = tid >> 6, l = tid & 63;
  const int bh = blockIdx.y, b = bh >> 4, h = bh & 15, g = h >> 2;
  const int q0 = blockIdx.x * 64;

  short8 qf[4];
  {
    const unsigned short* qrow =
        qkv + (size_t)(b * 2048 + q0 + w * 16 + (l & 15)) * 3072 + h * 128;
#pragma unroll
    for (int kk = 0; kk < 4; ++kk)
      qf[kk] = *(const short8*)&qrow[kk * 32 + (l >> 4) * 8];
  }

  f32x4 o[8];
#pragma unroll
  for (int n = 0; n < 8; ++n) o[n] = (f32x4){0.f, 0.f, 0.f, 0.f};
  float m_r[4] = {-1e30f, -1e30f, -1e30f, -1e30f};
  float l_r[4] = {0.f, 0.f, 0.f, 0.f};

  const unsigned short* kbase = qkv + (size_t)(b * 2048) * 3072 + 2048 + g * 128;
  const unsigned short* vbase = vt + (size_t)(b * 4 + g) * 128 * 2048;

  for (int t = 0; t < 32; ++t) {
    const int kv0 = t * 64;
    __syncthreads();
#pragma unroll
    for (int i = 0; i < 4; ++i) {
      const int row = i * 16 + (tid >> 4), ce = (tid & 15) * 8;
      *(uint4*)&Kl[row * 136 + ce] = *(const uint4*)&kbase[(size_t)(kv0 + row) * 3072 + ce];
    }
#pragma unroll
    for (int i = 0; i < 4; ++i) {
      const int d = i * 32 + (tid >> 3), ce = (tid & 7) * 8;
      *(uint4*)&Vl[d * 72 + ce] = *(const uint4*)&vbase[(size_t)d * 2048 + kv0 + ce];
    }
    __syncthreads();

    f32x4 s[4];
#pragma unroll
    for (int c = 0; c < 4; ++c) s[c] = (f32x4){0.f, 0.f, 0.f, 0.f};
#pragma unroll
    for (int kk = 0; kk < 4; ++kk)
#pragma unroll
      for (int c = 0; c < 4; ++c) {
        short8 kf = *(const short8*)&Kl[(c * 16 + (l & 15)) * 136 + kk * 32 + (l >> 4) * 8];
        s[c] = __builtin_amdgcn_mfma_f32_16x16x32_bf16(qf[kk], kf, s[c], 0, 0, 0);
      }

    float alpha[4];
#pragma unroll
    for (int r = 0; r < 4; ++r) {
      float tm = fmaxf(fmaxf(s[0][r], s[1][r]), fmaxf(s[2][r], s[3][r]));
#pragma unroll
      for (int mm = 1; mm < 16; mm <<= 1) tm = fmaxf(tm, __shfl_xor(tm, mm));
      const float mn = fmaxf(m_r[r], tm);
      float ps = 0.f;
#pragma unroll
      for (int c = 0; c < 4; ++c) {
        const float p = __expf(s[c][r] - mn);
        s[c][r] = p;
        ps += p;
      }
#pragma unroll
      for (int mm = 1; mm < 16; mm <<= 1) ps += __shfl_xor(ps, mm);
      alpha[r] = __expf(m_r[r] - mn);
      l_r[r] = l_r[r] * alpha[r] + ps;
      m_r[r] = mn;
    }
#pragma unroll
    for (int n = 0; n < 8; ++n)
#pragma unroll
      for (int r = 0; r < 4; ++r) o[n][r] *= alpha[r];

#pragma unroll
    for (int c = 0; c < 4; ++c)
#pragma unroll
      for (int r = 0; r < 4; ++r)
        Pl[w * 1152 + ((l >> 4) * 4 + r) * 72 + c * 16 + (l & 15)] = f2bf(s[c][r]);
    __syncthreads();

#pragma unroll
    for (int kk = 0; kk < 2; ++kk) {
      short8 pf = *(const short8*)&Pl[w * 1152 + (l & 15) * 72 + kk * 32 + (l >> 4) * 8];
#pragma unroll
      for (int n = 0; n < 8; ++n) {
        short8 vf = *(const short8*)&Vl[(n * 16 + (l & 15)) * 72 + kk * 32 + (l >> 4) * 8];
        o[n] = __builtin_amdgcn_mfma_f32_16x16x32_bf16(pf, vf, o[n], 0, 0, 0);
      }
    }
  }

  unsigned short* orow = out + (size_t)(b * 2048 + q0 + w * 16) * 2048 + h * 128;
#pragma unroll
  for (int r = 0; r < 4; ++r) {
    const float inv = 1.f / l_r[r];
    const int row = (l >> 4) * 4 + r;
#pragma unroll
    for (int n = 0; n < 8; ++n)
      orow[(size_t)row * 2048 + n * 16 + (l & 15)] = f2bf(o[n][r] * inv);
  }
}

// ---------------------------------------------------------------------------
// Row LayerNorm (block per row): optional bias-add, optional SiLU, then LN.
template <int NC, bool BIAS, bool SILU, bool OUTF32>
__global__ __launch_bounds__(256) void ln_row(const unsigned short* __restrict__ src,
                                              unsigned short* __restrict__ dstb,
                                              float* __restrict__ dstf,
                                              const float* __restrict__ gamma,
                                              const float* __restrict__ beta,
                                              const float* __restrict__ bias) {
  constexpr int E = NC / 256;
  const int row = blockIdx.x, tid = threadIdx.x;
  const size_t base = (size_t)row * NC + tid * E;
  float v[E];
#pragma unroll
  for (int c = 0; c < E / 8; ++c) {
    uint4 u = *(const uint4*)(src + base + c * 8);
    const unsigned short* us = (const unsigned short*)&u;
#pragma unroll
    for (int j = 0; j < 8; ++j) v[c * 8 + j] = bf2f(us[j]);
  }
  if constexpr (BIAS) {
#pragma unroll
    for (int i = 0; i < E; ++i) v[i] += bias[tid * E + i];
  }
  if constexpr (SILU) {
#pragma unroll
    for (int i = 0; i < E; ++i) v[i] = v[i] / (1.f + __expf(-v[i]));
  }
  float s = 0.f, q = 0.f;
#pragma unroll
  for (int i = 0; i < E; ++i) {
    s += v[i];
    q += v[i] * v[i];
  }
#pragma unroll
  for (int m = 1; m < 64; m <<= 1) {
    s += __shfl_xor(s, m);
    q += __shfl_xor(q, m);
  }
  __shared__ float rs[4], rq[4];
  if ((tid & 63) == 0) {
    rs[tid >> 6] = s;
    rq[tid >> 6] = q;
  }
  __syncthreads();
  s = rs[0] + rs[1] + rs[2] + rs[3];
  q = rq[0] + rq[1] + rq[2] + rq[3];
  const float mean = s / NC;
  const float rstd = rsqrtf(q / NC - mean * mean + 1e-5f);
#pragma unroll
  for (int i = 0; i < E; ++i)
    v[i] = (v[i] - mean) * rstd * gamma[tid * E + i] + beta[tid * E + i];
  if constexpr (OUTF32) {
#pragma unroll
    for (int c = 0; c < E / 4; ++c) {
      float4 f = {v[c * 4], v[c * 4 + 1], v[c * 4 + 2], v[c * 4 + 3]};
      *(float4*)(dstf + base + c * 4) = f;
    }
  } else {
#pragma unroll
    for (int c = 0; c < E / 8; ++c) {
      uint4 u;
      unsigned* up = (unsigned*)&u;
#pragma unroll
      for (int j = 0; j < 4; ++j)
        up[j] = (unsigned)f2bf(v[c * 8 + j * 2]) | ((unsigned)f2bf(v[c * 8 + j * 2 + 1]) << 16);
      *(uint4*)(dstb + base + c * 8) = u;
    }
  }
}

// ---------------------------------------------------------------------------
extern "C" void kernel_launch(void* const* d_in, const int* in_sizes, int n_in,
                              void* d_out, int out_size, void* d_ws, size_t ws_size,
                              hipStream_t stream) {
  (void)in_sizes; (void)n_in; (void)out_size; (void)ws_size;
  const float* x     = (const float*)d_in[0];
  const float* wq    = (const float*)d_in[1];
  const float* wk    = (const float*)d_in[2];
  const float* wv    = (const float*)d_in[3];
  const float* wo    = (const float*)d_in[4];
  const float* ln1_g = (const float*)d_in[5];
  const float* ln1_b = (const float*)d_in[6];
  const float* w1    = (const float*)d_in[7];
  const float* b1    = (const float*)d_in[8];
  const float* lnf_g = (const float*)d_in[9];
  const float* lnf_b = (const float*)d_in[10];
  const float* w2    = (const float*)d_in[11];
  const float* b2    = (const float*)d_in[12];

  unsigned short* ws = (unsigned short*)d_ws;
  unsigned short* wqkvT  = ws;                                  // [3072][2048]
  unsigned short* woT    = wqkvT  + (size_t)3072 * 2048;        // [2048][2048]
  unsigned short* w1T    = woT    + (size_t)2048 * 2048;        // [8192][2048]
  unsigned short* w2T    = w1T    + (size_t)8192 * 2048;        // [2048][8192]
  unsigned short* xb     = w2T    + (size_t)2048 * 8192;        // x bf16; later o/h
  unsigned short* qkv    = xb     + (size_t)4096 * 2048;        // [4096][3072]; later y
  unsigned short* vt     = qkv    + (size_t)4096 * 3072;        // [8][128][2048]
  unsigned short* attn_o = vt     + (size_t)4096 * 512;         // [4096][2048]
  unsigned short* f1     = attn_o + (size_t)4096 * 2048;        // [4096][8192]

  // allow >64KB dynamic LDS for the pipelined GEMMs (idempotent, not captured)
  (void)hipFuncSetAttribute((const void*)gemm256<256>,
                            hipFuncAttributeMaxDynamicSharedMemorySize, 131072);
  (void)hipFuncSetAttribute((const void*)gemm256<128>,
                            hipFuncAttributeMaxDynamicSharedMemorySize, 98304);

  const dim3 tb(32, 8);
  cast_f32_bf16<<<8192, 256, 0, stream>>>(x, xb, 4096 * 2048);
  transcast<<<dim3(64, 64),  tb, 0, stream>>>(wq, wqkvT, 2048, 2048, 2048, 0);
  transcast<<<dim3(16, 64),  tb, 0, stream>>>(wk, wqkvT, 2048, 512, 2048, 2048);
  transcast<<<dim3(16, 64),  tb, 0, stream>>>(wv, wqkvT, 2048, 512, 2048, 2560);
  transcast<<<dim3(64, 64),  tb, 0, stream>>>(wo, woT, 2048, 2048, 2048, 0);
  transcast<<<dim3(256, 64), tb, 0, stream>>>(w1, w1T, 2048, 8192, 2048, 0);
  transcast<<<dim3(64, 256), tb, 0, stream>>>(w2, w2T, 8192, 2048, 8192, 0);

  // fused QKV projection (M=4096 N=3072 K=2048)
  gemm256<256><<<dim3(12, 16), 512, 131072, stream>>>(xb, wqkvT, qkv, 4096, 3072, 2048);
  l2norm_qk<<<20480, 256, 0, stream>>>(qkv);
  vtrans<<<8192, 256, 0, stream>>>(qkv, vt);
  attn_kernel<<<dim3(32, 32), 256, 0, stream>>>(qkv, vt, attn_o);
  // O projection (N=2048: BN=128 -> 256 blocks, full machine)
  gemm256<128><<<dim3(16, 16), 512, 98304, stream>>>(attn_o, woT, xb, 4096, 2048, 2048);
  ln_row<2048, false, false, false><<<4096, 256, 0, stream>>>(xb, xb, nullptr, ln1_g, ln1_b, nullptr);
  // FFN1 (M=4096 N=8192 K=2048)
  gemm256<256><<<dim3(32, 16), 512, 131072, stream>>>(xb, w1T, f1, 4096, 8192, 2048);
  ln_row<8192, true, true, false><<<4096, 256, 0, stream>>>(f1, f1, nullptr, lnf_g, lnf_b, b1);
  // FFN2 (M=4096 N=2048 K=8192: BN=128)
  gemm256<128><<<dim3(16, 16), 512, 98304, stream>>>(f1, w2T, qkv, 4096, 2048, 8192);
  ln_row<2048, true, false, true><<<4096, 256, 0, stream>>>(qkv, nullptr, (float*)d_out, ln1_g, ln1_b, b2);
}

// Round 3
// 651.264 us; speedup vs baseline: 1.3748x; 1.1497x over previous
//
#include <hip/hip_runtime.h>

// ---------------------------------------------------------------------------
// ZambaSharedBlock: GQA attention block w/ qk-l2norm + FFN + 3 LayerNorms
// B=2 S=2048 DIM=2048 H=16 G=4 DH=128 FF=8192, non-causal, QK_SCALE=10
// Round 3: m214-style attention (8 warps x 32q, 32x32 MFMA, swapped QK^T,
// fixed-max in-register softmax, XOR-swizzled K/V^T LDS, reg-staged dbuf).
// GEMM/LN/prep unchanged from round 2.
// ---------------------------------------------------------------------------

typedef __attribute__((ext_vector_type(8))) short short8;
typedef __attribute__((ext_vector_type(4))) float f32x4;
typedef __attribute__((ext_vector_type(16))) float f32x16;

__device__ __forceinline__ unsigned short f2bf(float f) {
  unsigned int u = __builtin_bit_cast(unsigned int, f);
  u += 0x7FFFu + ((u >> 16) & 1u);           // RNE
  return (unsigned short)(u >> 16);
}
__device__ __forceinline__ float bf2f(unsigned short h) {
  unsigned int u = ((unsigned int)h) << 16;
  return __builtin_bit_cast(float, u);
}

typedef const void __attribute__((address_space(1)))* gas1_t;
typedef void __attribute__((address_space(3)))* las3_t;
#define GLDS16(g, l) \
  __builtin_amdgcn_global_load_lds((gas1_t)(const void*)(g), (las3_t)(void*)(l), 16, 0, 0)

// ---------------------------------------------------------------------------
__global__ __launch_bounds__(256) void cast_f32_bf16(const float* __restrict__ src,
                                                     unsigned short* __restrict__ dst,
                                                     int n) {
  int i = (blockIdx.x * 256 + threadIdx.x) * 4;
  if (i >= n) return;
  float4 f = *(const float4*)(src + i);
  uint2 u;
  u.x = (unsigned)f2bf(f.x) | ((unsigned)f2bf(f.y) << 16);
  u.y = (unsigned)f2bf(f.z) | ((unsigned)f2bf(f.w) << 16);
  *(uint2*)(dst + i) = u;
}

// ---------------------------------------------------------------------------
__global__ void transcast(const float* __restrict__ src, unsigned short* __restrict__ dst,
                          int R, int C, int dst_ld, int row_off) {
  __shared__ float t[32][33];
  const int tx = threadIdx.x, ty = threadIdx.y;
  const int c0 = blockIdx.x * 32, r0 = blockIdx.y * 32;
#pragma unroll
  for (int j = 0; j < 4; ++j)
    t[ty + j * 8][tx] = src[(size_t)(r0 + ty + j * 8) * C + c0 + tx];
  __syncthreads();
#pragma unroll
  for (int j = 0; j < 4; ++j)
    dst[(size_t)(row_off + c0 + ty + j * 8) * dst_ld + r0 + tx] = f2bf(t[tx][ty + j * 8]);
}

// ---------------------------------------------------------------------------
// Pipelined GEMM (round-2, unchanged): C = A * Bt^T, 256xBN tile, BK=64.
template <int BN>
__global__ __launch_bounds__(512, 2) void gemm256(const unsigned short* __restrict__ A,
                                                  const unsigned short* __restrict__ Bt,
                                                  unsigned short* __restrict__ C,
                                                  int M, int N, int K) {
  constexpr int NF = BN / 64;
  constexpr int HB = BN * 64;
  constexpr int RB = BN / 128;
  constexpr int AK1 = 16384 + HB;
  constexpr int BUFB = 32768 + 2 * HB;
  extern __shared__ char lds[];

  const int tid = threadIdx.x, l = tid & 63, w = tid >> 6;
  const int wr = w >> 2, wc = w & 3;
  const int brow = blockIdx.y * 256, bcol = blockIdx.x * BN;
  const unsigned short* Aa = A + (size_t)brow * K;
  const unsigned short* Bb = Bt + (size_t)bcol * K;
  const int NT = K >> 6;

  const int slot = l >> 4;
  const int rowA = wr * 128 + (l & 15);
  const int aRd = ((((rowA << 2) | slot) << 4) ^ ((rowA & 7) << 4));
  const int rowB = wc * (BN / 4) + (l & 15);
  const int bRd = ((((rowB << 2) | slot) << 4) ^ ((rowB & 7) << 4));

  f32x4 acc[8][NF];
#pragma unroll
  for (int m = 0; m < 8; ++m)
#pragma unroll
    for (int n = 0; n < NF; ++n) acc[m][n] = (f32x4){0.f, 0.f, 0.f, 0.f};

  auto stageA = [&](char* dst, int kofs) {
#pragma unroll
    for (int r = 0; r < 2; ++r) {
      const int g = r * 512 + tid;
      const int rw = ((g >> 3) << 1) | (((g >> 2) ^ (g >> 4)) & 1);
      const int sl = (g ^ rw) & 3;
      GLDS16(Aa + (size_t)rw * K + kofs + sl * 8, dst + g * 16);
    }
  };
  auto stageB = [&](char* dst, int kofs) {
#pragma unroll
    for (int r = 0; r < RB; ++r) {
      const int g = r * 512 + tid;
      const int rw = ((g >> 3) << 1) | (((g >> 2) ^ (g >> 4)) & 1);
      const int sl = (g ^ rw) & 3;
      GLDS16(Bb + (size_t)rw * K + kofs + sl * 8, dst + g * 16);
    }
  };

  stageA(lds, 0);
  stageB(lds + 16384, 0);
  stageA(lds + AK1, 32);
  stageB(lds + AK1 + 16384, 32);

  int kt = 0;
  for (int t = 0; t < NT; ++t) {
    char* curb = lds + (t & 1) * BUFB;
    char* nxtb = lds + ((t & 1) ^ 1) * BUFB;
    const int ktn = (t + 1 < NT) ? kt + 64 : 0;
    short8 af[4], bf[NF];

    if constexpr (BN == 256) asm volatile("s_waitcnt vmcnt(4)" ::: "memory");
    else                     asm volatile("s_waitcnt vmcnt(3)" ::: "memory");
    asm volatile("s_barrier" ::: "memory");
#pragma unroll
    for (int n = 0; n < NF; ++n) bf[n] = *(const short8*)(curb + 16384 + bRd + n * 1024);
#pragma unroll
    for (int m = 0; m < 4; ++m) af[m] = *(const short8*)(curb + aRd + m * 1024);
    stageA(nxtb, ktn);
    __builtin_amdgcn_s_setprio(1);
#pragma unroll
    for (int m = 0; m < 4; ++m)
#pragma unroll
      for (int n = 0; n < NF; ++n)
        acc[m][n] = __builtin_amdgcn_mfma_f32_16x16x32_bf16(af[m], bf[n], acc[m][n], 0, 0, 0);
    __builtin_amdgcn_s_setprio(0);

    asm volatile("s_barrier" ::: "memory");
#pragma unroll
    for (int m = 0; m < 4; ++m) af[m] = *(const short8*)(curb + aRd + (m + 4) * 1024);
    stageB(nxtb + 16384, ktn);
    __builtin_amdgcn_s_setprio(1);
#pragma unroll
    for (int m = 0; m < 4; ++m)
#pragma unroll
      for (int n = 0; n < NF; ++n)
        acc[m + 4][n] = __builtin_amdgcn_mfma_f32_16x16x32_bf16(af[m], bf[n], acc[m + 4][n], 0, 0, 0);
    __builtin_amdgcn_s_setprio(0);

    if constexpr (BN == 256) asm volatile("s_waitcnt vmcnt(4)" ::: "memory");
    else                     asm volatile("s_waitcnt vmcnt(3)" ::: "memory");
    asm volatile("s_barrier" ::: "memory");
#pragma unroll
    for (int n = 0; n < NF; ++n) bf[n] = *(const short8*)(curb + AK1 + 16384 + bRd + n * 1024);
#pragma unroll
    for (int m = 0; m < 4; ++m) af[m] = *(const short8*)(curb + AK1 + aRd + m * 1024);
    stageA(nxtb + AK1, ktn + 32);
    __builtin_amdgcn_s_setprio(1);
#pragma unroll
    for (int m = 0; m < 4; ++m)
#pragma unroll
      for (int n = 0; n < NF; ++n)
        acc[m][n] = __builtin_amdgcn_mfma_f32_16x16x32_bf16(af[m], bf[n], acc[m][n], 0, 0, 0);
    __builtin_amdgcn_s_setprio(0);

    asm volatile("s_barrier" ::: "memory");
#pragma unroll
    for (int m = 0; m < 4; ++m) af[m] = *(const short8*)(curb + AK1 + aRd + (m + 4) * 1024);
    stageB(nxtb + AK1 + 16384, ktn + 32);
    __builtin_amdgcn_s_setprio(1);
#pragma unroll
    for (int m = 0; m < 4; ++m)
#pragma unroll
      for (int n = 0; n < NF; ++n)
        acc[m + 4][n] = __builtin_amdgcn_mfma_f32_16x16x32_bf16(af[m], bf[n], acc[m + 4][n], 0, 0, 0);
    __builtin_amdgcn_s_setprio(0);

    kt += 64;
  }

#pragma unroll
  for (int m = 0; m < 8; ++m)
#pragma unroll
    for (int r = 0; r < 4; ++r) {
      const int row = brow + wr * 128 + m * 16 + (l >> 4) * 4 + r;
#pragma unroll
      for (int n = 0; n < NF; ++n) {
        const int col = bcol + wc * (BN / 4) + n * 16 + (l & 15);
        C[(size_t)row * N + col] = f2bf(acc[m][n][r]);
      }
    }
}

// ---------------------------------------------------------------------------
__global__ __launch_bounds__(256) void l2norm_qk(unsigned short* __restrict__ qkv) {
  const int wid = blockIdx.x * 4 + (threadIdx.x >> 6);
  const int l = threadIdx.x & 63;
  const int token = wid / 20, u = wid % 20;
  const int col = (u < 16) ? u * 128 : 2048 + (u - 16) * 128;
  unsigned short* p = qkv + (size_t)token * 3072 + col + l * 2;
  const float a = bf2f(p[0]), b = bf2f(p[1]);
  float ss = a * a + b * b;
#pragma unroll
  for (int m = 1; m < 64; m <<= 1) ss += __shfl_xor(ss, m);
  const float sc = ((u < 16) ? 10.f : 1.f) / fmaxf(sqrtf(ss), 1e-12f);
  p[0] = f2bf(a * sc);
  p[1] = f2bf(b * sc);
}

// ---------------------------------------------------------------------------
__global__ __launch_bounds__(256) void vtrans(const unsigned short* __restrict__ qkv,
                                              unsigned short* __restrict__ vt) {
  const int idx = blockIdx.x * 256 + threadIdx.x;
  const int s_ = idx & 2047;
  const int rest = idx >> 11;
  const int d = rest & 127;
  const int bg = rest >> 7;
  const int b = bg >> 2, g = bg & 3;
  vt[idx] = qkv[(size_t)(b * 2048 + s_) * 3072 + 2560 + g * 128 + d];
}

// ---------------------------------------------------------------------------
// Flash attention, m214 structure: 8 warps x QBLK=32, KVBLK=64, 32x32x16 MFMA.
// Swapped QK^T (S^T = K*Q^T) -> lane holds P[q=l&31][32 kv slots] -> softmax
// fully in-register with FIXED max 10 (|score| <= 10 by Cauchy-Schwarz since
// q,k l2-normed and scale folded into q). K LDS [64][256B] chunk-XOR-swizzled
// (chunk ^= row&15); V^T LDS [64 rowpairs][256B] similarly (uniform bank use).
// Reg-staged dbuf (T14): issue global loads before compute, ds_write after.
__global__ __launch_bounds__(512) void attn_kernel(const unsigned short* __restrict__ qkv,
                                                   const unsigned short* __restrict__ vt,
                                                   unsigned short* __restrict__ out) {
  extern __shared__ char smem[];  // 2 x (16KB K + 16KB V^T) = 64KB
  const int tid = threadIdx.x, w = tid >> 6, l = tid & 63;
  const int hi = l >> 5, l31 = l & 31;

  // XCD swizzle: 256 blocks, dispatcher XCD = id&7 -> give each XCD one (b,g)
  const int n = blockIdx.x;
  const int np = (n & 7) * 32 + (n >> 3);
  const int qi = np & 7, bh = np >> 3;
  const int b = bh >> 4, h = bh & 15, g = h >> 2;
  const int q0 = qi * 256;

  const unsigned short* kbase = qkv + (size_t)(b * 2048) * 3072 + 2048 + g * 128;
  const unsigned short* vbase = vt + (size_t)(b * 4 + g) * 128 * 2048;

  // Q fragments (B-operand of swapped QK^T): lane: q-row = l31, k = step*16+hi*8+j
  short8 qf[8];
  {
    const unsigned short* qrow = qkv + (size_t)(b * 2048 + q0 + w * 32 + l31) * 3072 + h * 128;
#pragma unroll
    for (int st = 0; st < 8; ++st)
      qf[st] = *(const short8*)&qrow[st * 16 + hi * 8];
  }

  f32x16 o[4];
#pragma unroll
  for (int d0 = 0; d0 < 4; ++d0)
#pragma unroll
    for (int i = 0; i < 16; ++i) o[d0][i] = 0.f;
  float l_part = 0.f;

  // staging thread->elements mapping
  const int krow = tid >> 3, kc = (tid & 7) * 2;          // K: row 0..63, chunks kc,kc+1
  const int vd = tid >> 2, vc = (tid & 3) * 2;            // V: d 0..127, chunks vc,vc+1
  const unsigned short* kg = kbase + (size_t)krow * 3072 + kc * 8;
  const unsigned short* vg = vbase + (size_t)vd * 2048 + vc * 8;
  // K LDS offsets (linear row*256B, chunk XOR row&15)
  const int ko0 = krow * 256 + ((kc ^ (krow & 15)) << 4);
  const int ko1 = krow * 256 + (((kc + 1) ^ (krow & 15)) << 4);
  // V^T LDS offsets: rowpair = d>>1, chunk_lin = (d&1)*8 + c, XOR rowpair&15
  const int vrp = vd >> 1, vcl = (vd & 1) * 8;
  const int vo0 = vrp * 256 + (((vcl + vc) ^ (vrp & 15)) << 4);
  const int vo1 = vrp * 256 + (((vcl + vc + 1) ^ (vrp & 15)) << 4);

  // prologue: stage tile 0 into buf 0
  {
    uint4 k0 = *(const uint4*)kg, k1 = *(const uint4*)(kg + 8);
    uint4 v0 = *(const uint4*)vg, v1 = *(const uint4*)(vg + 8);
    char* Kb = smem;
    char* Vb = smem + 16384;
    *(uint4*)(Kb + ko0) = k0; *(uint4*)(Kb + ko1) = k1;
    *(uint4*)(Vb + vo0) = v0; *(uint4*)(Vb + vo1) = v1;
  }
  __syncthreads();

  const int swzk = l31 & 15;
  for (int t = 0; t < 32; ++t) {
    // issue next tile's global loads early (T14): latency hides under compute
    uint4 k0, k1, v0, v1;
    const bool more = (t + 1) < 32;
    if (more) {
      const size_t kvo = (size_t)(t + 1) * 64;
      k0 = *(const uint4*)(kg + kvo * 3072);
      k1 = *(const uint4*)(kg + kvo * 3072 + 8);
      v0 = *(const uint4*)(vg + kvo);
      v1 = *(const uint4*)(vg + kvo + 8);
    }

    char* Kb = smem + (t & 1) * 32768;
    char* Vb = Kb + 16384;

    // ---- QK^T: S^T[kv][q], two 32-kv tiles, 8 k-steps
    f32x16 s0, s1;
#pragma unroll
    for (int i = 0; i < 16; ++i) { s0[i] = 0.f; s1[i] = 0.f; }
    __builtin_amdgcn_s_setprio(1);
#pragma unroll
    for (int st = 0; st < 8; ++st) {
      const int ch = st * 2 + hi;
      short8 kf0 = *(const short8*)(Kb + l31 * 256 + ((ch ^ swzk) << 4));
      short8 kf1 = *(const short8*)(Kb + (l31 + 32) * 256 + ((ch ^ swzk) << 4));
      s0 = __builtin_amdgcn_mfma_f32_32x32x16_bf16(kf0, qf[st], s0, 0, 0, 0);
      s1 = __builtin_amdgcn_mfma_f32_32x32x16_bf16(kf1, qf[st], s1, 0, 0, 0);
    }
    __builtin_amdgcn_s_setprio(0);

    // ---- softmax (fixed max = 10): P = exp(s - 10); per-lane partial sum
#pragma unroll
    for (int i = 0; i < 16; ++i) {
      s0[i] = __expf(s0[i] - 10.f);
      s1[i] = __expf(s1[i] - 10.f);
      l_part += s0[i] + s1[i];
    }

    // ---- P -> bf16 A-fragments pa[ks] (word exchange across lane halves)
    short8 pa[4];
#pragma unroll
    for (int ks = 0; ks < 4; ++ks) {
      const f32x16& sv = (ks < 2) ? s0 : s1;
      const int base = (ks & 1) * 8;
      auto pk = [](float x, float y) -> unsigned {
        unsigned ux = __builtin_bit_cast(unsigned, x);
        unsigned uy = __builtin_bit_cast(unsigned, y);
        return ((uy + 0x8000u) & 0xFFFF0000u) | ((ux + 0x8000u) >> 16);
      };
      unsigned a = pk(sv[base + 0], sv[base + 1]);
      unsigned bq = pk(sv[base + 4], sv[base + 5]);
      unsigned c = pk(sv[base + 2], sv[base + 3]);
      unsigned d = pk(sv[base + 6], sv[base + 7]);
      unsigned as = __shfl_xor(a, 32), bs = __shfl_xor(bq, 32);
      unsigned cs = __shfl_xor(c, 32), ds = __shfl_xor(d, 32);
      uint4 wv;
      wv.x = (l < 32) ? a : bs;
      wv.y = (l < 32) ? c : ds;
      wv.z = (l < 32) ? as : bq;
      wv.w = (l < 32) ? cs : d;
      pa[ks] = __builtin_bit_cast(short8, wv);
    }

    // ---- PV: O[q][d] += P * V (B-frag from V^T LDS)
    __builtin_amdgcn_s_setprio(1);
#pragma unroll
    for (int ks = 0; ks < 4; ++ks) {
#pragma unroll
      for (int d0 = 0; d0 < 4; ++d0) {
        const int dd = d0 * 32 + l31;
        const int rp = dd >> 1;
        const int cl = ((dd & 1) * 8 + ks * 2 + hi) ^ (rp & 15);
        short8 vf = *(const short8*)(Vb + rp * 256 + (cl << 4));
        o[d0] = __builtin_amdgcn_mfma_f32_32x32x16_bf16(pa[ks], vf, o[d0], 0, 0, 0);
      }
    }
    __builtin_amdgcn_s_setprio(0);

    __syncthreads();  // all reads of buf[t&1]... and prior writes consumed
    if (more) {
      char* Kn = smem + ((t + 1) & 1) * 32768;
      char* Vn = Kn + 16384;
      *(uint4*)(Kn + ko0) = k0; *(uint4*)(Kn + ko1) = k1;
      *(uint4*)(Vn + vo0) = v0; *(uint4*)(Vn + vo1) = v1;
    }
    __syncthreads();  // next buffer ready
  }

  // epilogue: combine lane-half sums, redistribute 1/l to O's q-rows, store
  float ltot = l_part + __shfl_xor(l_part, 32);
  float linv = 1.f / ltot;  // valid for q = l31 (both lane halves)
  const int tok_base = b * 2048 + q0 + w * 32;
#pragma unroll
  for (int r = 0; r < 16; ++r) {
    const int qr = (r & 3) + 8 * (r >> 2) + 4 * hi;
    const float li = __shfl(linv, qr);
    unsigned short* orow = out + (size_t)(tok_base + qr) * 2048 + h * 128 + l31;
#pragma unroll
    for (int d0 = 0; d0 < 4; ++d0)
      orow[d0 * 32] = f2bf(o[d0][r] * li);
  }
}

// ---------------------------------------------------------------------------
template <int NC, bool BIAS, bool SILU, bool OUTF32>
__global__ __launch_bounds__(256) void ln_row(const unsigned short* __restrict__ src,
                                              unsigned short* __restrict__ dstb,
                                              float* __restrict__ dstf,
                                              const float* __restrict__ gamma,
                                              const float* __restrict__ beta,
                                              const float* __restrict__ bias) {
  constexpr int E = NC / 256;
  const int row = blockIdx.x, tid = threadIdx.x;
  const size_t base = (size_t)row * NC + tid * E;
  float v[E];
#pragma unroll
  for (int c = 0; c < E / 8; ++c) {
    uint4 u = *(const uint4*)(src + base + c * 8);
    const unsigned short* us = (const unsigned short*)&u;
#pragma unroll
    for (int j = 0; j < 8; ++j) v[c * 8 + j] = bf2f(us[j]);
  }
  if constexpr (BIAS) {
#pragma unroll
    for (int i = 0; i < E; ++i) v[i] += bias[tid * E + i];
  }
  if constexpr (SILU) {
#pragma unroll
    for (int i = 0; i < E; ++i) v[i] = v[i] / (1.f + __expf(-v[i]));
  }
  float s = 0.f, q = 0.f;
#pragma unroll
  for (int i = 0; i < E; ++i) {
    s += v[i];
    q += v[i] * v[i];
  }
#pragma unroll
  for (int m = 1; m < 64; m <<= 1) {
    s += __shfl_xor(s, m);
    q += __shfl_xor(q, m);
  }
  __shared__ float rs[4], rq[4];
  if ((tid & 63) == 0) {
    rs[tid >> 6] = s;
    rq[tid >> 6] = q;
  }
  __syncthreads();
  s = rs[0] + rs[1] + rs[2] + rs[3];
  q = rq[0] + rq[1] + rq[2] + rq[3];
  const float mean = s / NC;
  const float rstd = rsqrtf(q / NC - mean * mean + 1e-5f);
#pragma unroll
  for (int i = 0; i < E; ++i)
    v[i] = (v[i] - mean) * rstd * gamma[tid * E + i] + beta[tid * E + i];
  if constexpr (OUTF32) {
#pragma unroll
    for (int c = 0; c < E / 4; ++c) {
      float4 f = {v[c * 4], v[c * 4 + 1], v[c * 4 + 2], v[c * 4 + 3]};
      *(float4*)(dstf + base + c * 4) = f;
    }
  } else {
#pragma unroll
    for (int c = 0; c < E / 8; ++c) {
      uint4 u;
      unsigned* up = (unsigned*)&u;
#pragma unroll
      for (int j = 0; j < 4; ++j)
        up[j] = (unsigned)f2bf(v[c * 8 + j * 2]) | ((unsigned)f2bf(v[c * 8 + j * 2 + 1]) << 16);
      *(uint4*)(dstb + base + c * 8) = u;
    }
  }
}

// ---------------------------------------------------------------------------
extern "C" void kernel_launch(void* const* d_in, const int* in_sizes, int n_in,
                              void* d_out, int out_size, void* d_ws, size_t ws_size,
                              hipStream_t stream) {
  (void)in_sizes; (void)n_in; (void)out_size; (void)ws_size;
  const float* x     = (const float*)d_in[0];
  const float* wq    = (const float*)d_in[1];
  const float* wk    = (const float*)d_in[2];
  const float* wv    = (const float*)d_in[3];
  const float* wo    = (const float*)d_in[4];
  const float* ln1_g = (const float*)d_in[5];
  const float* ln1_b = (const float*)d_in[6];
  const float* w1    = (const float*)d_in[7];
  const float* b1    = (const float*)d_in[8];
  const float* lnf_g = (const float*)d_in[9];
  const float* lnf_b = (const float*)d_in[10];
  const float* w2    = (const float*)d_in[11];
  const float* b2    = (const float*)d_in[12];

  unsigned short* ws = (unsigned short*)d_ws;
  unsigned short* wqkvT  = ws;                                  // [3072][2048]
  unsigned short* woT    = wqkvT  + (size_t)3072 * 2048;        // [2048][2048]
  unsigned short* w1T    = woT    + (size_t)2048 * 2048;        // [8192][2048]
  unsigned short* w2T    = w1T    + (size_t)8192 * 2048;        // [2048][8192]
  unsigned short* xb     = w2T    + (size_t)2048 * 8192;        // x bf16; later o/h
  unsigned short* qkv    = xb     + (size_t)4096 * 2048;        // [4096][3072]; later y
  unsigned short* vt     = qkv    + (size_t)4096 * 3072;        // [8][128][2048]
  unsigned short* attn_o = vt     + (size_t)4096 * 512;         // [4096][2048]
  unsigned short* f1     = attn_o + (size_t)4096 * 2048;        // [4096][8192]

  (void)hipFuncSetAttribute((const void*)gemm256<256>,
                            hipFuncAttributeMaxDynamicSharedMemorySize, 131072);
  (void)hipFuncSetAttribute((const void*)gemm256<128>,
                            hipFuncAttributeMaxDynamicSharedMemorySize, 98304);
  (void)hipFuncSetAttribute((const void*)attn_kernel,
                            hipFuncAttributeMaxDynamicSharedMemorySize, 65536);

  const dim3 tb(32, 8);
  cast_f32_bf16<<<8192, 256, 0, stream>>>(x, xb, 4096 * 2048);
  transcast<<<dim3(64, 64),  tb, 0, stream>>>(wq, wqkvT, 2048, 2048, 2048, 0);
  transcast<<<dim3(16, 64),  tb, 0, stream>>>(wk, wqkvT, 2048, 512, 2048, 2048);
  transcast<<<dim3(16, 64),  tb, 0, stream>>>(wv, wqkvT, 2048, 512, 2048, 2560);
  transcast<<<dim3(64, 64),  tb, 0, stream>>>(wo, woT, 2048, 2048, 2048, 0);
  transcast<<<dim3(256, 64), tb, 0, stream>>>(w1, w1T, 2048, 8192, 2048, 0);
  transcast<<<dim3(64, 256), tb, 0, stream>>>(w2, w2T, 8192, 2048, 8192, 0);

  gemm256<256><<<dim3(12, 16), 512, 131072, stream>>>(xb, wqkvT, qkv, 4096, 3072, 2048);
  l2norm_qk<<<20480, 256, 0, stream>>>(qkv);
  vtrans<<<8192, 256, 0, stream>>>(qkv, vt);
  attn_kernel<<<256, 512, 65536, stream>>>(qkv, vt, attn_o);
  gemm256<128><<<dim3(16, 16), 512, 98304, stream>>>(attn_o, woT, xb, 4096, 2048, 2048);
  ln_row<2048, false, false, false><<<4096, 256, 0, stream>>>(xb, xb, nullptr, ln1_g, ln1_b, nullptr);
  gemm256<256><<<dim3(32, 16), 512, 131072, stream>>>(xb, w1T, f1, 4096, 8192, 2048);
  ln_row<8192, true, true, false><<<4096, 256, 0, stream>>>(f1, f1, nullptr, lnf_g, lnf_b, b1);
  gemm256<128><<<dim3(16, 16), 512, 98304, stream>>>(f1, w2T, qkv, 4096, 2048, 8192);
  ln_row<2048, true, false, true><<<4096, 256, 0, stream>>>(qkv, nullptr, (float*)d_out, ln1_g, ln1_b, b2);
}

// Round 4
// 644.961 us; speedup vs baseline: 1.3882x; 1.0098x over previous
//
#include <hip/hip_runtime.h>

// ---------------------------------------------------------------------------
// ZambaSharedBlock: GQA attention block w/ qk-l2norm + FFN + 3 LayerNorms
// B=2 S=2048 DIM=2048 H=16 G=4 DH=128 FF=8192, non-causal, QK_SCALE=10
// Round 4: ring-3 deep-prefetch GEMM for N=2048 (O-proj, FFN2) + XCD-cluster
// block swizzles on all GEMMs. Attention/LN/prep unchanged from round 3.
// ---------------------------------------------------------------------------

typedef __attribute__((ext_vector_type(8))) short short8;
typedef __attribute__((ext_vector_type(4))) float f32x4;
typedef __attribute__((ext_vector_type(16))) float f32x16;

__device__ __forceinline__ unsigned short f2bf(float f) {
  unsigned int u = __builtin_bit_cast(unsigned int, f);
  u += 0x7FFFu + ((u >> 16) & 1u);           // RNE
  return (unsigned short)(u >> 16);
}
__device__ __forceinline__ float bf2f(unsigned short h) {
  unsigned int u = ((unsigned int)h) << 16;
  return __builtin_bit_cast(float, u);
}

typedef const void __attribute__((address_space(1)))* gas1_t;
typedef void __attribute__((address_space(3)))* las3_t;
#define GLDS16(g, l) \
  __builtin_amdgcn_global_load_lds((gas1_t)(const void*)(g), (las3_t)(void*)(l), 16, 0, 0)

// ---------------------------------------------------------------------------
__global__ __launch_bounds__(256) void cast_f32_bf16(const float* __restrict__ src,
                                                     unsigned short* __restrict__ dst,
                                                     int n) {
  int i = (blockIdx.x * 256 + threadIdx.x) * 4;
  if (i >= n) return;
  float4 f = *(const float4*)(src + i);
  uint2 u;
  u.x = (unsigned)f2bf(f.x) | ((unsigned)f2bf(f.y) << 16);
  u.y = (unsigned)f2bf(f.z) | ((unsigned)f2bf(f.w) << 16);
  *(uint2*)(dst + i) = u;
}

// ---------------------------------------------------------------------------
__global__ void transcast(const float* __restrict__ src, unsigned short* __restrict__ dst,
                          int R, int C, int dst_ld, int row_off) {
  __shared__ float t[32][33];
  const int tx = threadIdx.x, ty = threadIdx.y;
  const int c0 = blockIdx.x * 32, r0 = blockIdx.y * 32;
#pragma unroll
  for (int j = 0; j < 4; ++j)
    t[ty + j * 8][tx] = src[(size_t)(r0 + ty + j * 8) * C + c0 + tx];
  __syncthreads();
#pragma unroll
  for (int j = 0; j < 4; ++j)
    dst[(size_t)(row_off + c0 + ty + j * 8) * dst_ld + r0 + tx] = f2bf(t[tx][ty + j * 8]);
}

// ---------------------------------------------------------------------------
// Pipelined GEMM (BN=256): C = A * Bt^T, 256x256 tile, BK=64, dbuf depth-2.
// XCD swizzle: m204 bijective chunked remap over column-major block order.
template <int BN>
__global__ __launch_bounds__(512, 2) void gemm256(const unsigned short* __restrict__ A,
                                                  const unsigned short* __restrict__ Bt,
                                                  unsigned short* __restrict__ C,
                                                  int M, int N, int K) {
  constexpr int NF = BN / 64;
  constexpr int HB = BN * 64;
  constexpr int RB = BN / 128;
  constexpr int AK1 = 16384 + HB;
  constexpr int BUFB = 32768 + 2 * HB;
  extern __shared__ char lds[];

  const int tid = threadIdx.x, l = tid & 63, w = tid >> 6;
  const int wr = w >> 2, wc = w & 3;
  // XCD chunked remap (nwg % 8 == 0 for all our grids)
  const int gx = gridDim.x, gy = gridDim.y;
  const int did = blockIdx.y * gx + blockIdx.x;
  const int q = (gx * gy) >> 3;
  const int tcm = (did & 7) * q + (did >> 3);
  const int brow = (tcm % gy) * 256, bcol = (tcm / gy) * BN;
  const unsigned short* Aa = A + (size_t)brow * K;
  const unsigned short* Bb = Bt + (size_t)bcol * K;
  const int NT = K >> 6;

  const int slot = l >> 4;
  const int rowA = wr * 128 + (l & 15);
  const int aRd = ((((rowA << 2) | slot) << 4) ^ ((rowA & 7) << 4));
  const int rowB = wc * (BN / 4) + (l & 15);
  const int bRd = ((((rowB << 2) | slot) << 4) ^ ((rowB & 7) << 4));

  f32x4 acc[8][NF];
#pragma unroll
  for (int m = 0; m < 8; ++m)
#pragma unroll
    for (int n = 0; n < NF; ++n) acc[m][n] = (f32x4){0.f, 0.f, 0.f, 0.f};

  auto stageA = [&](char* dst, int kofs) {
#pragma unroll
    for (int r = 0; r < 2; ++r) {
      const int g = r * 512 + tid;
      const int rw = ((g >> 3) << 1) | (((g >> 2) ^ (g >> 4)) & 1);
      const int sl = (g ^ rw) & 3;
      GLDS16(Aa + (size_t)rw * K + kofs + sl * 8, dst + g * 16);
    }
  };
  auto stageB = [&](char* dst, int kofs) {
#pragma unroll
    for (int r = 0; r < RB; ++r) {
      const int g = r * 512 + tid;
      const int rw = ((g >> 3) << 1) | (((g >> 2) ^ (g >> 4)) & 1);
      const int sl = (g ^ rw) & 3;
      GLDS16(Bb + (size_t)rw * K + kofs + sl * 8, dst + g * 16);
    }
  };

  stageA(lds, 0);
  stageB(lds + 16384, 0);
  stageA(lds + AK1, 32);
  stageB(lds + AK1 + 16384, 32);

  int kt = 0;
  for (int t = 0; t < NT; ++t) {
    char* curb = lds + (t & 1) * BUFB;
    char* nxtb = lds + ((t & 1) ^ 1) * BUFB;
    const int ktn = (t + 1 < NT) ? kt + 64 : 0;
    short8 af[4], bf[NF];

    if constexpr (BN == 256) asm volatile("s_waitcnt vmcnt(4)" ::: "memory");
    else                     asm volatile("s_waitcnt vmcnt(3)" ::: "memory");
    asm volatile("s_barrier" ::: "memory");
#pragma unroll
    for (int n = 0; n < NF; ++n) bf[n] = *(const short8*)(curb + 16384 + bRd + n * 1024);
#pragma unroll
    for (int m = 0; m < 4; ++m) af[m] = *(const short8*)(curb + aRd + m * 1024);
    stageA(nxtb, ktn);
    __builtin_amdgcn_s_setprio(1);
#pragma unroll
    for (int m = 0; m < 4; ++m)
#pragma unroll
      for (int n = 0; n < NF; ++n)
        acc[m][n] = __builtin_amdgcn_mfma_f32_16x16x32_bf16(af[m], bf[n], acc[m][n], 0, 0, 0);
    __builtin_amdgcn_s_setprio(0);

    asm volatile("s_barrier" ::: "memory");
#pragma unroll
    for (int m = 0; m < 4; ++m) af[m] = *(const short8*)(curb + aRd + (m + 4) * 1024);
    stageB(nxtb + 16384, ktn);
    __builtin_amdgcn_s_setprio(1);
#pragma unroll
    for (int m = 0; m < 4; ++m)
#pragma unroll
      for (int n = 0; n < NF; ++n)
        acc[m + 4][n] = __builtin_amdgcn_mfma_f32_16x16x32_bf16(af[m], bf[n], acc[m + 4][n], 0, 0, 0);
    __builtin_amdgcn_s_setprio(0);

    if constexpr (BN == 256) asm volatile("s_waitcnt vmcnt(4)" ::: "memory");
    else                     asm volatile("s_waitcnt vmcnt(3)" ::: "memory");
    asm volatile("s_barrier" ::: "memory");
#pragma unroll
    for (int n = 0; n < NF; ++n) bf[n] = *(const short8*)(curb + AK1 + 16384 + bRd + n * 1024);
#pragma unroll
    for (int m = 0; m < 4; ++m) af[m] = *(const short8*)(curb + AK1 + aRd + m * 1024);
    stageA(nxtb + AK1, ktn + 32);
    __builtin_amdgcn_s_setprio(1);
#pragma unroll
    for (int m = 0; m < 4; ++m)
#pragma unroll
      for (int n = 0; n < NF; ++n)
        acc[m][n] = __builtin_amdgcn_mfma_f32_16x16x32_bf16(af[m], bf[n], acc[m][n], 0, 0, 0);
    __builtin_amdgcn_s_setprio(0);

    asm volatile("s_barrier" ::: "memory");
#pragma unroll
    for (int m = 0; m < 4; ++m) af[m] = *(const short8*)(curb + AK1 + aRd + (m + 4) * 1024);
    stageB(nxtb + AK1 + 16384, ktn + 32);
    __builtin_amdgcn_s_setprio(1);
#pragma unroll
    for (int m = 0; m < 4; ++m)
#pragma unroll
      for (int n = 0; n < NF; ++n)
        acc[m + 4][n] = __builtin_amdgcn_mfma_f32_16x16x32_bf16(af[m], bf[n], acc[m + 4][n], 0, 0, 0);
    __builtin_amdgcn_s_setprio(0);

    kt += 64;
  }

#pragma unroll
  for (int m = 0; m < 8; ++m)
#pragma unroll
    for (int r = 0; r < 4; ++r) {
      const int row = brow + wr * 128 + m * 16 + (l >> 4) * 4 + r;
#pragma unroll
      for (int n = 0; n < NF; ++n) {
        const int col = bcol + wc * (BN / 4) + n * 16 + (l & 15);
        C[(size_t)row * N + col] = f2bf(acc[m][n][r]);
      }
    }
}

// ---------------------------------------------------------------------------
// Ring-3 deep-prefetch GEMM: 256x128 tile, BK=64, prefetch distance 2 tiles
// (~1200+ cyc > 900-cyc HBM latency). LDS 3 x 48KB. Grid must be (16,16);
// XCD swizzle: 4-brow x 8-bcol cluster per XCD (bijective).
// Buffer layout: A_k0 @0 (16K), B_k0 @16384 (8K), A_k1 @24576, B_k1 @40960.
// 6 loads/thread/tile -> one s_waitcnt vmcnt(6) per tile.
__global__ __launch_bounds__(512, 1) void gemm128r3(const unsigned short* __restrict__ A,
                                                    const unsigned short* __restrict__ Bt,
                                                    unsigned short* __restrict__ C,
                                                    int M, int N, int K) {
  constexpr int BUFB = 49152;
  extern __shared__ char lds[];
  const int tid = threadIdx.x, l = tid & 63, w = tid >> 6;
  const int wr = w >> 2, wc = w & 3;
  const int did = blockIdx.y * 16 + blockIdx.x;
  const int xcd = did & 7, idx = did >> 3;
  const int brow = ((xcd >> 1) * 4 + (idx & 3)) * 256;
  const int bcol = ((xcd & 1) * 8 + (idx >> 2)) * 128;
  const unsigned short* Aa = A + (size_t)brow * K;
  const unsigned short* Bb = Bt + (size_t)bcol * K;
  const int NT = K >> 6;

  const int slot = l >> 4;
  const int rowA = wr * 128 + (l & 15);
  const int aRd = ((((rowA << 2) | slot) << 4) ^ ((rowA & 7) << 4));
  const int rowB = wc * 32 + (l & 15);
  const int bRd = ((((rowB << 2) | slot) << 4) ^ ((rowB & 7) << 4));

  f32x4 acc[8][2];
#pragma unroll
  for (int m = 0; m < 8; ++m)
#pragma unroll
    for (int n = 0; n < 2; ++n) acc[m][n] = (f32x4){0.f, 0.f, 0.f, 0.f};

  auto stageA = [&](char* dst, int kofs) {
#pragma unroll
    for (int r = 0; r < 2; ++r) {
      const int g = r * 512 + tid;
      const int rw = ((g >> 3) << 1) | (((g >> 2) ^ (g >> 4)) & 1);
      const int sl = (g ^ rw) & 3;
      GLDS16(Aa + (size_t)rw * K + kofs + sl * 8, dst + g * 16);
    }
  };
  auto stageB = [&](char* dst, int kofs) {
    const int g = tid;
    const int rw = ((g >> 3) << 1) | (((g >> 2) ^ (g >> 4)) & 1);
    const int sl = (g ^ rw) & 3;
    GLDS16(Bb + (size_t)rw * K + kofs + sl * 8, dst + g * 16);
  };

  // prologue: tile 0 -> buf0, tile 1 -> buf1 (12 loads outstanding)
  stageA(lds, 0);                  stageB(lds + 16384, 0);
  stageA(lds + 24576, 32);         stageB(lds + 40960, 32);
  stageA(lds + BUFB, 64);          stageB(lds + BUFB + 16384, 64);
  stageA(lds + BUFB + 24576, 96);  stageB(lds + BUFB + 40960, 96);

  char* b0 = lds;
  char* b1 = lds + BUFB;
  char* b2 = lds + 2 * BUFB;
  int kt2 = 128;  // K-offset of tile t+2
  for (int t = 0; t < NT; ++t) {
    char* cur = b0;
    char* nxt = b2;  // buffer of tile t+2 (freed by compute of tile t-1)
    const int kn = (t + 2 < NT) ? kt2 : 0;  // dummy re-stage of tile 0 at end
    short8 af[4], bf[2];

    // ---- phase 0: ks0 m0-3. Retire tile-t loads (6 newest = tile t+1's).
    asm volatile("s_waitcnt vmcnt(6)" ::: "memory");
    asm volatile("s_barrier" ::: "memory");
    bf[0] = *(const short8*)(cur + 16384 + bRd);
    bf[1] = *(const short8*)(cur + 16384 + bRd + 1024);
#pragma unroll
    for (int m = 0; m < 4; ++m) af[m] = *(const short8*)(cur + aRd + m * 1024);
    stageA(nxt, kn);
    stageB(nxt + 16384, kn);
    __builtin_amdgcn_s_setprio(1);
#pragma unroll
    for (int m = 0; m < 4; ++m)
#pragma unroll
      for (int n = 0; n < 2; ++n)
        acc[m][n] = __builtin_amdgcn_mfma_f32_16x16x32_bf16(af[m], bf[n], acc[m][n], 0, 0, 0);
    __builtin_amdgcn_s_setprio(0);

    // ---- phase 1: ks0 m4-7
    asm volatile("s_barrier" ::: "memory");
#pragma unroll
    for (int m = 0; m < 4; ++m) af[m] = *(const short8*)(cur + aRd + (m + 4) * 1024);
    stageA(nxt + 24576, kn + 32);
    stageB(nxt + 40960, kn + 32);
    __builtin_amdgcn_s_setprio(1);
#pragma unroll
    for (int m = 0; m < 4; ++m)
#pragma unroll
      for (int n = 0; n < 2; ++n)
        acc[m + 4][n] = __builtin_amdgcn_mfma_f32_16x16x32_bf16(af[m], bf[n], acc[m + 4][n], 0, 0, 0);
    __builtin_amdgcn_s_setprio(0);

    // ---- phase 2: ks1 m0-3 (whole tile already resident; no vmcnt)
    asm volatile("s_barrier" ::: "memory");
    bf[0] = *(const short8*)(cur + 40960 + bRd);
    bf[1] = *(const short8*)(cur + 40960 + bRd + 1024);
#pragma unroll
    for (int m = 0; m < 4; ++m) af[m] = *(const short8*)(cur + 24576 + aRd + m * 1024);
    __builtin_amdgcn_s_setprio(1);
#pragma unroll
    for (int m = 0; m < 4; ++m)
#pragma unroll
      for (int n = 0; n < 2; ++n)
        acc[m][n] = __builtin_amdgcn_mfma_f32_16x16x32_bf16(af[m], bf[n], acc[m][n], 0, 0, 0);
    __builtin_amdgcn_s_setprio(0);

    // ---- phase 3: ks1 m4-7
    asm volatile("s_barrier" ::: "memory");
#pragma unroll
    for (int m = 0; m < 4; ++m) af[m] = *(const short8*)(cur + 24576 + aRd + (m + 4) * 1024);
    __builtin_amdgcn_s_setprio(1);
#pragma unroll
    for (int m = 0; m < 4; ++m)
#pragma unroll
      for (int n = 0; n < 2; ++n)
        acc[m + 4][n] = __builtin_amdgcn_mfma_f32_16x16x32_bf16(af[m], bf[n], acc[m + 4][n], 0, 0, 0);
    __builtin_amdgcn_s_setprio(0);

    char* tmp = b0; b0 = b1; b1 = b2; b2 = tmp;
    kt2 += 64;
  }

#pragma unroll
  for (int m = 0; m < 8; ++m)
#pragma unroll
    for (int r = 0; r < 4; ++r) {
      const int row = brow + wr * 128 + m * 16 + (l >> 4) * 4 + r;
#pragma unroll
      for (int n = 0; n < 2; ++n) {
        const int col = bcol + wc * 32 + n * 16 + (l & 15);
        C[(size_t)row * N + col] = f2bf(acc[m][n][r]);
      }
    }
}

// ---------------------------------------------------------------------------
__global__ __launch_bounds__(256) void l2norm_qk(unsigned short* __restrict__ qkv) {
  const int wid = blockIdx.x * 4 + (threadIdx.x >> 6);
  const int l = threadIdx.x & 63;
  const int token = wid / 20, u = wid % 20;
  const int col = (u < 16) ? u * 128 : 2048 + (u - 16) * 128;
  unsigned short* p = qkv + (size_t)token * 3072 + col + l * 2;
  const float a = bf2f(p[0]), b = bf2f(p[1]);
  float ss = a * a + b * b;
#pragma unroll
  for (int m = 1; m < 64; m <<= 1) ss += __shfl_xor(ss, m);
  const float sc = ((u < 16) ? 10.f : 1.f) / fmaxf(sqrtf(ss), 1e-12f);
  p[0] = f2bf(a * sc);
  p[1] = f2bf(b * sc);
}

// ---------------------------------------------------------------------------
__global__ __launch_bounds__(256) void vtrans(const unsigned short* __restrict__ qkv,
                                              unsigned short* __restrict__ vt) {
  const int idx = blockIdx.x * 256 + threadIdx.x;
  const int s_ = idx & 2047;
  const int rest = idx >> 11;
  const int d = rest & 127;
  const int bg = rest >> 7;
  const int b = bg >> 2, g = bg & 3;
  vt[idx] = qkv[(size_t)(b * 2048 + s_) * 3072 + 2560 + g * 128 + d];
}

// ---------------------------------------------------------------------------
// Flash attention (round-3 structure, unchanged)
__global__ __launch_bounds__(512) void attn_kernel(const unsigned short* __restrict__ qkv,
                                                   const unsigned short* __restrict__ vt,
                                                   unsigned short* __restrict__ out) {
  extern __shared__ char smem[];
  const int tid = threadIdx.x, w = tid >> 6, l = tid & 63;
  const int hi = l >> 5, l31 = l & 31;

  const int n = blockIdx.x;
  const int np = (n & 7) * 32 + (n >> 3);
  const int qi = np & 7, bh = np >> 3;
  const int b = bh >> 4, h = bh & 15, g = h >> 2;
  const int q0 = qi * 256;

  const unsigned short* kbase = qkv + (size_t)(b * 2048) * 3072 + 2048 + g * 128;
  const unsigned short* vbase = vt + (size_t)(b * 4 + g) * 128 * 2048;

  short8 qf[8];
  {
    const unsigned short* qrow = qkv + (size_t)(b * 2048 + q0 + w * 32 + l31) * 3072 + h * 128;
#pragma unroll
    for (int st = 0; st < 8; ++st)
      qf[st] = *(const short8*)&qrow[st * 16 + hi * 8];
  }

  f32x16 o[4];
#pragma unroll
  for (int d0 = 0; d0 < 4; ++d0)
#pragma unroll
    for (int i = 0; i < 16; ++i) o[d0][i] = 0.f;
  float l_part = 0.f;

  const int krow = tid >> 3, kc = (tid & 7) * 2;
  const int vd = tid >> 2, vc = (tid & 3) * 2;
  const unsigned short* kg = kbase + (size_t)krow * 3072 + kc * 8;
  const unsigned short* vg = vbase + (size_t)vd * 2048 + vc * 8;
  const int ko0 = krow * 256 + ((kc ^ (krow & 15)) << 4);
  const int ko1 = krow * 256 + (((kc + 1) ^ (krow & 15)) << 4);
  const int vrp = vd >> 1, vcl = (vd & 1) * 8;
  const int vo0 = vrp * 256 + (((vcl + vc) ^ (vrp & 15)) << 4);
  const int vo1 = vrp * 256 + (((vcl + vc + 1) ^ (vrp & 15)) << 4);

  {
    uint4 k0 = *(const uint4*)kg, k1 = *(const uint4*)(kg + 8);
    uint4 v0 = *(const uint4*)vg, v1 = *(const uint4*)(vg + 8);
    char* Kb = smem;
    char* Vb = smem + 16384;
    *(uint4*)(Kb + ko0) = k0; *(uint4*)(Kb + ko1) = k1;
    *(uint4*)(Vb + vo0) = v0; *(uint4*)(Vb + vo1) = v1;
  }
  __syncthreads();

  const int swzk = l31 & 15;
  for (int t = 0; t < 32; ++t) {
    uint4 k0, k1, v0, v1;
    const bool more = (t + 1) < 32;
    if (more) {
      const size_t kvo = (size_t)(t + 1) * 64;
      k0 = *(const uint4*)(kg + kvo * 3072);
      k1 = *(const uint4*)(kg + kvo * 3072 + 8);
      v0 = *(const uint4*)(vg + kvo);
      v1 = *(const uint4*)(vg + kvo + 8);
    }

    char* Kb = smem + (t & 1) * 32768;
    char* Vb = Kb + 16384;

    f32x16 s0, s1;
#pragma unroll
    for (int i = 0; i < 16; ++i) { s0[i] = 0.f; s1[i] = 0.f; }
    __builtin_amdgcn_s_setprio(1);
#pragma unroll
    for (int st = 0; st < 8; ++st) {
      const int ch = st * 2 + hi;
      short8 kf0 = *(const short8*)(Kb + l31 * 256 + ((ch ^ swzk) << 4));
      short8 kf1 = *(const short8*)(Kb + (l31 + 32) * 256 + ((ch ^ swzk) << 4));
      s0 = __builtin_amdgcn_mfma_f32_32x32x16_bf16(kf0, qf[st], s0, 0, 0, 0);
      s1 = __builtin_amdgcn_mfma_f32_32x32x16_bf16(kf1, qf[st], s1, 0, 0, 0);
    }
    __builtin_amdgcn_s_setprio(0);

#pragma unroll
    for (int i = 0; i < 16; ++i) {
      s0[i] = __expf(s0[i] - 10.f);
      s1[i] = __expf(s1[i] - 10.f);
      l_part += s0[i] + s1[i];
    }

    short8 pa[4];
#pragma unroll
    for (int ks = 0; ks < 4; ++ks) {
      const f32x16& sv = (ks < 2) ? s0 : s1;
      const int base = (ks & 1) * 8;
      auto pk = [](float x, float y) -> unsigned {
        unsigned ux = __builtin_bit_cast(unsigned, x);
        unsigned uy = __builtin_bit_cast(unsigned, y);
        return ((uy + 0x8000u) & 0xFFFF0000u) | ((ux + 0x8000u) >> 16);
      };
      unsigned a = pk(sv[base + 0], sv[base + 1]);
      unsigned bq = pk(sv[base + 4], sv[base + 5]);
      unsigned c = pk(sv[base + 2], sv[base + 3]);
      unsigned d = pk(sv[base + 6], sv[base + 7]);
      unsigned as = __shfl_xor(a, 32), bs = __shfl_xor(bq, 32);
      unsigned cs = __shfl_xor(c, 32), ds = __shfl_xor(d, 32);
      uint4 wv;
      wv.x = (l < 32) ? a : bs;
      wv.y = (l < 32) ? c : ds;
      wv.z = (l < 32) ? as : bq;
      wv.w = (l < 32) ? cs : d;
      pa[ks] = __builtin_bit_cast(short8, wv);
    }

    __builtin_amdgcn_s_setprio(1);
#pragma unroll
    for (int ks = 0; ks < 4; ++ks) {
#pragma unroll
      for (int d0 = 0; d0 < 4; ++d0) {
        const int dd = d0 * 32 + l31;
        const int rp = dd >> 1;
        const int cl = ((dd & 1) * 8 + ks * 2 + hi) ^ (rp & 15);
        short8 vf = *(const short8*)(Vb + rp * 256 + (cl << 4));
        o[d0] = __builtin_amdgcn_mfma_f32_32x32x16_bf16(pa[ks], vf, o[d0], 0, 0, 0);
      }
    }
    __builtin_amdgcn_s_setprio(0);

    __syncthreads();
    if (more) {
      char* Kn = smem + ((t + 1) & 1) * 32768;
      char* Vn = Kn + 16384;
      *(uint4*)(Kn + ko0) = k0; *(uint4*)(Kn + ko1) = k1;
      *(uint4*)(Vn + vo0) = v0; *(uint4*)(Vn + vo1) = v1;
    }
    __syncthreads();
  }

  float ltot = l_part + __shfl_xor(l_part, 32);
  float linv = 1.f / ltot;
  const int tok_base = b * 2048 + q0 + w * 32;
#pragma unroll
  for (int r = 0; r < 16; ++r) {
    const int qr = (r & 3) + 8 * (r >> 2) + 4 * hi;
    const float li = __shfl(linv, qr);
    unsigned short* orow = out + (size_t)(tok_base + qr) * 2048 + h * 128 + l31;
#pragma unroll
    for (int d0 = 0; d0 < 4; ++d0)
      orow[d0 * 32] = f2bf(o[d0][r] * li);
  }
}

// ---------------------------------------------------------------------------
template <int NC, bool BIAS, bool SILU, bool OUTF32>
__global__ __launch_bounds__(256) void ln_row(const unsigned short* __restrict__ src,
                                              unsigned short* __restrict__ dstb,
                                              float* __restrict__ dstf,
                                              const float* __restrict__ gamma,
                                              const float* __restrict__ beta,
                                              const float* __restrict__ bias) {
  constexpr int E = NC / 256;
  const int row = blockIdx.x, tid = threadIdx.x;
  const size_t base = (size_t)row * NC + tid * E;
  float v[E];
#pragma unroll
  for (int c = 0; c < E / 8; ++c) {
    uint4 u = *(const uint4*)(src + base + c * 8);
    const unsigned short* us = (const unsigned short*)&u;
#pragma unroll
    for (int j = 0; j < 8; ++j) v[c * 8 + j] = bf2f(us[j]);
  }
  if constexpr (BIAS) {
#pragma unroll
    for (int i = 0; i < E; ++i) v[i] += bias[tid * E + i];
  }
  if constexpr (SILU) {
#pragma unroll
    for (int i = 0; i < E; ++i) v[i] = v[i] / (1.f + __expf(-v[i]));
  }
  float s = 0.f, q = 0.f;
#pragma unroll
  for (int i = 0; i < E; ++i) {
    s += v[i];
    q += v[i] * v[i];
  }
#pragma unroll
  for (int m = 1; m < 64; m <<= 1) {
    s += __shfl_xor(s, m);
    q += __shfl_xor(q, m);
  }
  __shared__ float rs[4], rq[4];
  if ((tid & 63) == 0) {
    rs[tid >> 6] = s;
    rq[tid >> 6] = q;
  }
  __syncthreads();
  s = rs[0] + rs[1] + rs[2] + rs[3];
  q = rq[0] + rq[1] + rq[2] + rq[3];
  const float mean = s / NC;
  const float rstd = rsqrtf(q / NC - mean * mean + 1e-5f);
#pragma unroll
  for (int i = 0; i < E; ++i)
    v[i] = (v[i] - mean) * rstd * gamma[tid * E + i] + beta[tid * E + i];
  if constexpr (OUTF32) {
#pragma unroll
    for (int c = 0; c < E / 4; ++c) {
      float4 f = {v[c * 4], v[c * 4 + 1], v[c * 4 + 2], v[c * 4 + 3]};
      *(float4*)(dstf + base + c * 4) = f;
    }
  } else {
#pragma unroll
    for (int c = 0; c < E / 8; ++c) {
      uint4 u;
      unsigned* up = (unsigned*)&u;
#pragma unroll
      for (int j = 0; j < 4; ++j)
        up[j] = (unsigned)f2bf(v[c * 8 + j * 2]) | ((unsigned)f2bf(v[c * 8 + j * 2 + 1]) << 16);
      *(uint4*)(dstb + base + c * 8) = u;
    }
  }
}

// ---------------------------------------------------------------------------
extern "C" void kernel_launch(void* const* d_in, const int* in_sizes, int n_in,
                              void* d_out, int out_size, void* d_ws, size_t ws_size,
                              hipStream_t stream) {
  (void)in_sizes; (void)n_in; (void)out_size; (void)ws_size;
  const float* x     = (const float*)d_in[0];
  const float* wq    = (const float*)d_in[1];
  const float* wk    = (const float*)d_in[2];
  const float* wv    = (const float*)d_in[3];
  const float* wo    = (const float*)d_in[4];
  const float* ln1_g = (const float*)d_in[5];
  const float* ln1_b = (const float*)d_in[6];
  const float* w1    = (const float*)d_in[7];
  const float* b1    = (const float*)d_in[8];
  const float* lnf_g = (const float*)d_in[9];
  const float* lnf_b = (const float*)d_in[10];
  const float* w2    = (const float*)d_in[11];
  const float* b2    = (const float*)d_in[12];

  unsigned short* ws = (unsigned short*)d_ws;
  unsigned short* wqkvT  = ws;                                  // [3072][2048]
  unsigned short* woT    = wqkvT  + (size_t)3072 * 2048;        // [2048][2048]
  unsigned short* w1T    = woT    + (size_t)2048 * 2048;        // [8192][2048]
  unsigned short* w2T    = w1T    + (size_t)8192 * 2048;        // [2048][8192]
  unsigned short* xb     = w2T    + (size_t)2048 * 8192;        // x bf16; later o/h
  unsigned short* qkv    = xb     + (size_t)4096 * 2048;        // [4096][3072]; later y
  unsigned short* vt     = qkv    + (size_t)4096 * 3072;        // [8][128][2048]
  unsigned short* attn_o = vt     + (size_t)4096 * 512;         // [4096][2048]
  unsigned short* f1     = attn_o + (size_t)4096 * 2048;        // [4096][8192]

  (void)hipFuncSetAttribute((const void*)gemm256<256>,
                            hipFuncAttributeMaxDynamicSharedMemorySize, 131072);
  (void)hipFuncSetAttribute((const void*)gemm128r3,
                            hipFuncAttributeMaxDynamicSharedMemorySize, 147456);
  (void)hipFuncSetAttribute((const void*)attn_kernel,
                            hipFuncAttributeMaxDynamicSharedMemorySize, 65536);

  const dim3 tb(32, 8);
  cast_f32_bf16<<<8192, 256, 0, stream>>>(x, xb, 4096 * 2048);
  transcast<<<dim3(64, 64),  tb, 0, stream>>>(wq, wqkvT, 2048, 2048, 2048, 0);
  transcast<<<dim3(16, 64),  tb, 0, stream>>>(wk, wqkvT, 2048, 512, 2048, 2048);
  transcast<<<dim3(16, 64),  tb, 0, stream>>>(wv, wqkvT, 2048, 512, 2048, 2560);
  transcast<<<dim3(64, 64),  tb, 0, stream>>>(wo, woT, 2048, 2048, 2048, 0);
  transcast<<<dim3(256, 64), tb, 0, stream>>>(w1, w1T, 2048, 8192, 2048, 0);
  transcast<<<dim3(64, 256), tb, 0, stream>>>(w2, w2T, 8192, 2048, 8192, 0);

  gemm256<256><<<dim3(12, 16), 512, 131072, stream>>>(xb, wqkvT, qkv, 4096, 3072, 2048);
  l2norm_qk<<<20480, 256, 0, stream>>>(qkv);
  vtrans<<<8192, 256, 0, stream>>>(qkv, vt);
  attn_kernel<<<256, 512, 65536, stream>>>(qkv, vt, attn_o);
  // O projection: ring-3 deep prefetch (grid must be 16x16)
  gemm128r3<<<dim3(16, 16), 512, 147456, stream>>>(attn_o, woT, xb, 4096, 2048, 2048);
  ln_row<2048, false, false, false><<<4096, 256, 0, stream>>>(xb, xb, nullptr, ln1_g, ln1_b, nullptr);
  gemm256<256><<<dim3(32, 16), 512, 131072, stream>>>(xb, w1T, f1, 4096, 8192, 2048);
  ln_row<8192, true, true, false><<<4096, 256, 0, stream>>>(f1, f1, nullptr, lnf_g, lnf_b, b1);
  // FFN2: ring-3 deep prefetch
  gemm128r3<<<dim3(16, 16), 512, 147456, stream>>>(f1, w2T, qkv, 4096, 2048, 8192);
  ln_row<2048, true, false, true><<<4096, 256, 0, stream>>>(qkv, nullptr, (float*)d_out, ln1_g, ln1_b, b2);
}